// Round 10
// baseline (216.991 us; speedup 1.0000x reference)
//
#include <hip/hip_runtime.h>

// Fused MHA block: out = LayerNorm(x + MHA(x)).  B=4, S=2048, D=1024, H=16, dk=64.
// bf16 MFMA internal, fp32 I/O.
//
// Round 10 = Round 9 + split-K attn at NATURAL register pressure:
//  R9 attn was grid-limited (512 blocks = 2/CU = 16 waves/CU, occ 36%).
//  Split kpos into 2 halves (grid z=2, 1024 blocks = 4/CU = 32 waves/CU).
//  No-max softmax makes partials linear: O = O0+O1, l = l0+l1 (R7 validated
//  numerics; R7's 8x regression was the forced __launch_bounds__(512,8)->
//  32 VGPR spill, NOT split-K). NO min-wave launch bound here: VGPR stays ~60.
//  Partial O (bf16, unnormalized) -> d_out scratch (33.5 MB exact fit,
//  consumed by combine before gemm<1> overwrites); partial l -> dead Wqkv.

#define SEQ 2048
#define DMODEL 1024
#define NH 16
#define DK 64
#define NROWS 8192  // B*S

typedef unsigned short u16;
typedef unsigned int u32;
typedef __bf16 bf16;
typedef bf16 bf16x8 __attribute__((ext_vector_type(8)));
typedef float f32x4 __attribute__((ext_vector_type(4)));
typedef float f32x16 __attribute__((ext_vector_type(16)));
typedef unsigned u32x2 __attribute__((ext_vector_type(2)));

__device__ inline u16 bfbits(float f) { return __builtin_bit_cast(u16, (bf16)f); }
__device__ inline u32 packbf2(float a, float b) {
    return (u32)bfbits(a) | ((u32)bfbits(b) << 16);
}
__device__ inline float bf2f(u16 h) {
    union { u32 u; float f; } v; v.u = (u32)h << 16; return v.f;
}

// Schraudolph exp2: s in (-120, 60); balanced rel error +-2.9%, cancels in
// softmax normalization. v_fma + v_cvt, full-rate VALU (no TRANS pipe).
__device__ inline float sexp2(float s) {
    return __builtin_bit_cast(float, (u32)(int)fmaf(s, 8388608.0f, 1064986823.0f));
}

// async global->LDS, 16B per lane; LDS dest = wave-uniform base + lane*16
__device__ inline void gload16(const u16* g, u16* l) {
    __builtin_amdgcn_global_load_lds(
        (const __attribute__((address_space(1))) u32*)g,
        (__attribute__((address_space(3))) u32*)l, 16, 0, 0);
}

// cross-half exchange (validated rounds 2-9)
__device__ inline void plswap(u32& a, u32& b) {
#if __has_builtin(__builtin_amdgcn_permlane32_swap)
    u32x2 r = __builtin_amdgcn_permlane32_swap(a, b, false, false);
    a = r[0]; b = r[1];
#else
    u32 xa = __shfl_xor(a, 32), xb = __shfl_xor(b, 32);
    int hi = (threadIdx.x & 63) >> 5;
    u32 na = hi ? xb : a;
    u32 nb = hi ? b : xa;
    a = na; b = nb;
#endif
}

// ---------------- fp32 -> bf16 converts ----------------
__global__ __launch_bounds__(256) void cvt_f32_bf16(const float* __restrict__ in,
                                                    u16* __restrict__ out, int n) {
    int i = (blockIdx.x * 256 + threadIdx.x) * 4;
    if (i >= n) return;
    float4 v = *(const float4*)(in + i);
    ushort4 o;
    o.x = bfbits(v.x); o.y = bfbits(v.y); o.z = bfbits(v.z); o.w = bfbits(v.w);
    *(ushort4*)(out + i) = o;
}

__global__ __launch_bounds__(256) void cvt4_w(const float* __restrict__ w0,
                                              const float* __restrict__ w1,
                                              const float* __restrict__ w2,
                                              const float* __restrict__ w3,
                                              u16* __restrict__ o0, u16* __restrict__ o1,
                                              u16* __restrict__ o2, u16* __restrict__ o3) {
    const float* in;
    u16* out;
    switch (blockIdx.y) {
        case 0: in = w0; out = o0; break;
        case 1: in = w1; out = o1; break;
        case 2: in = w2; out = o2; break;
        default: in = w3; out = o3; break;
    }
    int i = (blockIdx.x * 256 + threadIdx.x) * 4;
    float4 v = *(const float4*)(in + i);
    ushort4 o;
    o.x = bfbits(v.x); o.y = bfbits(v.y); o.z = bfbits(v.z); o.w = bfbits(v.w);
    *(ushort4*)(out + i) = o;
}

// ---------------- GEMM: C[M,N] = A[M,K=1024] @ W[N,K]^T (+epilogue) ----------------
// 128x128 tile, BK=64, global_load_lds staging, XOR-swizzled via pre-swizzled source.
// EPI 0: QKV. Q/K quadrants: direct stores. V quadrant: LDS-transpose bounce.
template <int EPI>
__global__ __launch_bounds__(256) void gemm_bt(
    const u16* __restrict__ A, const u16* __restrict__ Bm,
    const float* __restrict__ bias0, const float* __restrict__ bias1,
    const float* __restrict__ bias2,
    u16* __restrict__ Qo, u16* __restrict__ Ko, u16* __restrict__ Vo,
    const float* __restrict__ xres, float* __restrict__ yout) {
    __shared__ __align__(16) u16 smem[16384];   // As = [0,8192), Bs = [8192,16384)
    u16* As = smem;
    u16* Bs = smem + 8192;

    const int tid  = threadIdx.x;
    const int lane = tid & 63;
    const int w    = tid >> 6;
    const int wr   = (w >> 1) * 64;
    const int wc   = (w & 1) * 64;
    const int l16  = lane & 15;
    const int lq   = lane >> 4;
    const int m0   = blockIdx.x * 128;
    const int n0   = blockIdx.y * 128;

    f32x4 acc[4][4];
#pragma unroll
    for (int m = 0; m < 4; m++)
#pragma unroll
        for (int n = 0; n < 4; n++) {
            f32x4 z = {0.f, 0.f, 0.f, 0.f};
            acc[m][n] = z;
        }

    const int l8r = lane >> 3;
    const int sch = (lane & 7) ^ l8r;
    const u16* a_g = A  + (size_t)(m0 + w * 32 + l8r) * 1024 + sch * 8;
    const u16* b_g = Bm + (size_t)(n0 + w * 32 + l8r) * 1024 + sch * 8;

    for (int k0 = 0; k0 < 1024; k0 += 64) {
        __syncthreads();
#pragma unroll
        for (int i = 0; i < 4; i++) {
            gload16(a_g + (size_t)i * 8192 + k0, As + (w * 32 + i * 8) * 64);
            gload16(b_g + (size_t)i * 8192 + k0, Bs + (w * 32 + i * 8) * 64);
        }
        __syncthreads();

#pragma unroll
        for (int kk = 0; kk < 2; kk++) {
            bf16x8 af[4], bfr[4];
#pragma unroll
            for (int m = 0; m < 4; m++)
                af[m] = *(const bf16x8*)&As[(wr + m * 16 + l16) * 64 +
                                            (((kk << 2) | lq) ^ (l16 & 7)) * 8];
#pragma unroll
            for (int n = 0; n < 4; n++)
                bfr[n] = *(const bf16x8*)&Bs[(wc + n * 16 + l16) * 64 +
                                             (((kk << 2) | lq) ^ (l16 & 7)) * 8];
            __builtin_amdgcn_s_setprio(1);
#pragma unroll
            for (int m = 0; m < 4; m++)
#pragma unroll
                for (int n = 0; n < 4; n++)
                    acc[m][n] = __builtin_amdgcn_mfma_f32_16x16x32_bf16(
                        af[m], bfr[n], acc[m][n], 0, 0, 0);
            __builtin_amdgcn_s_setprio(0);
        }
    }

    if (EPI == 0 && n0 >= 2048) {
        // ---- V quadrant: LDS-transpose bounce -> coalesced V^T stores ----
        const int e0 = n0 - 2048;
        __syncthreads();
#pragma unroll
        for (int m = 0; m < 4; m++)
#pragma unroll
            for (int n = 0; n < 4; n++) {
                const int col = wc + n * 16 + l16;       // local e
                const int row = wr + lq * 4 + m * 16;    // local s, 4-aligned
                const float bias = bias2[e0 + col];
                ushort4 pk;
                pk.x = bfbits(acc[m][n][0] + bias);
                pk.y = bfbits(acc[m][n][1] + bias);
                pk.z = bfbits(acc[m][n][2] + bias);
                pk.w = bfbits(acc[m][n][3] + bias);
                *(ushort4*)&smem[col * 128 + (row ^ ((col & 7) << 3))] = pk;
            }
        __syncthreads();
        const int b = m0 >> 11;
        const int sbase = m0 & 2047;
#pragma unroll
        for (int i = 0; i < 8; i++) {
            const int c = tid + 256 * i;
            const int col = c >> 4;
            const int s0 = (c & 15) * 8;
            uint4 val = *(const uint4*)&smem[col * 128 + (s0 ^ ((col & 7) << 3))];
            const int eg = e0 + col;
            const int bh = b * NH + (eg >> 6);
            *(uint4*)&Vo[((size_t)bh * DK + (eg & 63)) * SEQ + sbase + s0] = val;
        }
        return;
    }

    const int rbase = m0 + wr + lq * 4;
    const int cbase = n0 + wc + l16;
#pragma unroll
    for (int m = 0; m < 4; m++)
#pragma unroll
        for (int n = 0; n < 4; n++) {
            const int col = cbase + n * 16;
#pragma unroll
            for (int r = 0; r < 4; r++) {
                const int row = rbase + m * 16 + r;
                float v = acc[m][n][r];
                if (EPI == 0) {
                    const int which = col >> 10;   // 0=Q, 1=K (V handled above)
                    const int e = col & 1023;
                    v += (which == 0) ? bias0[e] : bias1[e];
                    if (which == 0) v *= 0.18033688011112042f;  // 1/sqrt(dk) * log2(e)
                    const int h = e >> 6, d = e & 63;
                    const int b = row >> 11, s = row & 2047;
                    const int bh = b * NH + h;
                    if (which == 0)
                        Qo[((size_t)bh * SEQ + s) * DK + d] = bfbits(v);
                    else
                        Ko[((size_t)bh * SEQ + s) * DK + d] = bfbits(v);
                } else {
                    v += bias0[col] + xres[(size_t)row * DMODEL + col];
                    yout[(size_t)row * DMODEL + col] = v;
                }
            }
        }
}

// ---------------- flash attention, split-K, swapped-QK^T, no-max softmax ----------------
// grid (B*H, S/256, 2), 512 thr = 8 waves; wave w owns q rows [q0, q0+32).
// ks-block covers kpos [ks*1024, (ks+1)*1024) = 16 tiles of 64.
// Writes UNNORMALIZED partial O (bf16) + partial l (fp32); combine normalizes.
__global__ __launch_bounds__(512) void attn(const u16* __restrict__ Qb,
                                            const u16* __restrict__ Kb,
                                            const u16* __restrict__ Vtb,
                                            u16* __restrict__ pO,
                                            float* __restrict__ lG) {
    // K bufs 2x[64][64] elems 0..8191; V^T bufs 2x[64][64] elems 8192..16383.
    __shared__ __align__(16) u16 smem[16384];

    const int tid  = threadIdx.x;
    const int lane = tid & 63;
    const int w    = tid >> 6;
    const int q    = lane & 31;
    const int hi   = lane >> 5;
    const int bh   = blockIdx.x;
    const int ks   = blockIdx.z;
    const int q0   = blockIdx.y * 256 + w * 32;

    const u16* qp = Qb + ((size_t)bh * SEQ + q0 + q) * DK + hi * 8;
    bf16x8 qf0 = *(const bf16x8*)(qp);
    bf16x8 qf1 = *(const bf16x8*)(qp + 16);
    bf16x8 qf2 = *(const bf16x8*)(qp + 32);
    bf16x8 qf3 = *(const bf16x8*)(qp + 48);

    // staging: wave w stages K rows [w*8, w*8+8) and V^T rows [w*8, w*8+8).
    const int l8r = lane >> 3;
    const int sch = (lane & 7) ^ l8r;
    const u16* kg = Kb  + ((size_t)bh * SEQ + ks * 1024 + w * 8 + l8r) * 64 + sch * 8;
    const u16* vg = Vtb + ((size_t)bh * DK + w * 8 + l8r) * SEQ + ks * 1024 + sch * 8;
    u16* kl = smem + w * 512;
    u16* vl = smem + 8192 + w * 512;

    f32x16 oacc0, oacc1;
#pragma unroll
    for (int r = 0; r < 16; r++) { oacc0[r] = 0.f; oacc1[r] = 0.f; }
    f32x16 fzero;
#pragma unroll
    for (int r = 0; r < 16; r++) fzero[r] = 0.f;
    float l_ = 0.f;

    gload16(kg, kl);
    gload16(vg, vl);
    __syncthreads();

    for (int t = 0; t < 16; t++) {
        if (t < 15) {
            gload16(kg + (size_t)(t + 1) * 4096, kl + ((t + 1) & 1) * 4096);
            gload16(vg + (size_t)(t + 1) * 64,  vl + ((t + 1) & 1) * 4096);
        }
        const u16* Kl = smem + (t & 1) * 4096;
        const u16* Vl = smem + 8192 + (t & 1) * 4096;

        // ---- S^T = K . Q^T ----
        f32x16 sacc0, sacc1;
        {
            bf16x8 k00 = *(const bf16x8*)&Kl[(q)      * 64 + ((0 | hi) ^ (q & 7)) * 8];
            bf16x8 k01 = *(const bf16x8*)&Kl[(q)      * 64 + ((2 | hi) ^ (q & 7)) * 8];
            bf16x8 k02 = *(const bf16x8*)&Kl[(q)      * 64 + ((4 | hi) ^ (q & 7)) * 8];
            bf16x8 k03 = *(const bf16x8*)&Kl[(q)      * 64 + ((6 | hi) ^ (q & 7)) * 8];
            bf16x8 k10 = *(const bf16x8*)&Kl[(q + 32) * 64 + ((0 | hi) ^ (q & 7)) * 8];
            bf16x8 k11 = *(const bf16x8*)&Kl[(q + 32) * 64 + ((2 | hi) ^ (q & 7)) * 8];
            bf16x8 k12 = *(const bf16x8*)&Kl[(q + 32) * 64 + ((4 | hi) ^ (q & 7)) * 8];
            bf16x8 k13 = *(const bf16x8*)&Kl[(q + 32) * 64 + ((6 | hi) ^ (q & 7)) * 8];
            __builtin_amdgcn_s_setprio(1);
            sacc0 = __builtin_amdgcn_mfma_f32_32x32x16_bf16(k00, qf0, fzero, 0, 0, 0);
            sacc1 = __builtin_amdgcn_mfma_f32_32x32x16_bf16(k10, qf0, fzero, 0, 0, 0);
            sacc0 = __builtin_amdgcn_mfma_f32_32x32x16_bf16(k01, qf1, sacc0, 0, 0, 0);
            sacc1 = __builtin_amdgcn_mfma_f32_32x32x16_bf16(k11, qf1, sacc1, 0, 0, 0);
            sacc0 = __builtin_amdgcn_mfma_f32_32x32x16_bf16(k02, qf2, sacc0, 0, 0, 0);
            sacc1 = __builtin_amdgcn_mfma_f32_32x32x16_bf16(k12, qf2, sacc1, 0, 0, 0);
            sacc0 = __builtin_amdgcn_mfma_f32_32x32x16_bf16(k03, qf3, sacc0, 0, 0, 0);
            sacc1 = __builtin_amdgcn_mfma_f32_32x32x16_bf16(k13, qf3, sacc1, 0, 0, 0);
            __builtin_amdgcn_s_setprio(0);
        }

        // ---- no-max softmax via Schraudolph exp2 ----
#pragma unroll
        for (int r = 0; r < 16; r++) sacc0[r] = sexp2(sacc0[r]);
#pragma unroll
        for (int r = 0; r < 16; r++) sacc1[r] = sexp2(sacc1[r]);
        {
            float s0 = ((sacc0[0] + sacc0[1]) + (sacc0[2] + sacc0[3])) +
                       ((sacc0[4] + sacc0[5]) + (sacc0[6] + sacc0[7]));
            float s1 = ((sacc0[8] + sacc0[9]) + (sacc0[10] + sacc0[11])) +
                       ((sacc0[12] + sacc0[13]) + (sacc0[14] + sacc0[15]));
            float s2 = ((sacc1[0] + sacc1[1]) + (sacc1[2] + sacc1[3])) +
                       ((sacc1[4] + sacc1[5]) + (sacc1[6] + sacc1[7]));
            float s3 = ((sacc1[8] + sacc1[9]) + (sacc1[10] + sacc1[11])) +
                       ((sacc1[12] + sacc1[13]) + (sacc1[14] + sacc1[15]));
            l_ += (s0 + s1) + (s2 + s3);
        }

        // ---- pack P to bf16 + permlane exchange -> P^T B-frags ----
        u32 wa[8], wb[8];
#pragma unroll
        for (int i = 0; i < 8; i++) wa[i] = packbf2(sacc0[2 * i], sacc0[2 * i + 1]);
#pragma unroll
        for (int i = 0; i < 8; i++) wb[i] = packbf2(sacc1[2 * i], sacc1[2 * i + 1]);
        plswap(wa[0], wa[2]); plswap(wa[1], wa[3]);
        plswap(wa[4], wa[6]); plswap(wa[5], wa[7]);
        plswap(wb[0], wb[2]); plswap(wb[1], wb[3]);
        plswap(wb[4], wb[6]); plswap(wb[5], wb[7]);
        union { u32 u[4]; bf16x8 v; } pf0, pf1, pf2, pf3;
        pf0.u[0] = wa[0]; pf0.u[1] = wa[1]; pf0.u[2] = wa[2]; pf0.u[3] = wa[3];
        pf1.u[0] = wa[4]; pf1.u[1] = wa[5]; pf1.u[2] = wa[6]; pf1.u[3] = wa[7];
        pf2.u[0] = wb[0]; pf2.u[1] = wb[1]; pf2.u[2] = wb[2]; pf2.u[3] = wb[3];
        pf3.u[0] = wb[4]; pf3.u[1] = wb[5]; pf3.u[2] = wb[6]; pf3.u[3] = wb[7];

        // ---- O^T += V^T . P^T ----
        {
            bf16x8 v00 = *(const bf16x8*)&Vl[(q)      * 64 + ((0 | hi) ^ (q & 7)) * 8];
            bf16x8 v01 = *(const bf16x8*)&Vl[(q)      * 64 + ((2 | hi) ^ (q & 7)) * 8];
            bf16x8 v02 = *(const bf16x8*)&Vl[(q)      * 64 + ((4 | hi) ^ (q & 7)) * 8];
            bf16x8 v03 = *(const bf16x8*)&Vl[(q)      * 64 + ((6 | hi) ^ (q & 7)) * 8];
            bf16x8 v10 = *(const bf16x8*)&Vl[(q + 32) * 64 + ((0 | hi) ^ (q & 7)) * 8];
            bf16x8 v11 = *(const bf16x8*)&Vl[(q + 32) * 64 + ((2 | hi) ^ (q & 7)) * 8];
            bf16x8 v12 = *(const bf16x8*)&Vl[(q + 32) * 64 + ((4 | hi) ^ (q & 7)) * 8];
            bf16x8 v13 = *(const bf16x8*)&Vl[(q + 32) * 64 + ((6 | hi) ^ (q & 7)) * 8];
            __builtin_amdgcn_s_setprio(1);
            oacc0 = __builtin_amdgcn_mfma_f32_32x32x16_bf16(v00, pf0.v, oacc0, 0, 0, 0);
            oacc1 = __builtin_amdgcn_mfma_f32_32x32x16_bf16(v10, pf0.v, oacc1, 0, 0, 0);
            oacc0 = __builtin_amdgcn_mfma_f32_32x32x16_bf16(v01, pf1.v, oacc0, 0, 0, 0);
            oacc1 = __builtin_amdgcn_mfma_f32_32x32x16_bf16(v11, pf1.v, oacc1, 0, 0, 0);
            oacc0 = __builtin_amdgcn_mfma_f32_32x32x16_bf16(v02, pf2.v, oacc0, 0, 0, 0);
            oacc1 = __builtin_amdgcn_mfma_f32_32x32x16_bf16(v12, pf2.v, oacc1, 0, 0, 0);
            oacc0 = __builtin_amdgcn_mfma_f32_32x32x16_bf16(v03, pf3.v, oacc0, 0, 0, 0);
            oacc1 = __builtin_amdgcn_mfma_f32_32x32x16_bf16(v13, pf3.v, oacc1, 0, 0, 0);
            __builtin_amdgcn_s_setprio(0);
        }

        __syncthreads();
    }

    // ---- merge half-lane l partials once; write UNNORMALIZED partial O + l ----
    l_ = l_ + __shfl_xor(l_, 32);
    if (lane < 32) lG[((size_t)(ks * 64 + bh)) * SEQ + q0 + lane] = l_;

    const int wbase = w * 2048;
#pragma unroll
    for (int r = 0; r < 16; r++) {
        const int dk0 = (r & 3) + 8 * (r >> 2) + 4 * hi;
        const int dk1 = 32 + dk0;
        smem[wbase + q * 64 + (((dk0 >> 3) ^ (q & 7)) << 3) + (dk0 & 7)] = bfbits(oacc0[r]);
        smem[wbase + q * 64 + (((dk1 >> 3) ^ (q & 7)) << 3) + (dk1 & 7)] = bfbits(oacc1[r]);
    }
    __syncthreads();
    const int r4 = lane >> 1;
    const int cc = (lane & 1) * 4;
#pragma unroll
    for (int c = 0; c < 4; c++) {
        const int chunk = cc + c;
        uint4 val = *(const uint4*)&smem[wbase + r4 * 64 + ((chunk ^ (r4 & 7)) << 3)];
        *(uint4*)&pO[(((size_t)(ks * 64 + bh)) * SEQ + q0 + r4) * DK + chunk * 8] = val;
    }
}

// ---------------- split-K combine: ctx = (O0+O1)/(l0+l1) ----------------
__global__ __launch_bounds__(256) void combine(const u16* __restrict__ pO,
                                               const float* __restrict__ lG,
                                               u16* __restrict__ ctx) {
    const int t = blockIdx.x * 256 + threadIdx.x;
    const int chunk = t & 7;
    const int s = (t >> 3) & 2047;
    const int bh = t >> 14;
    const float inv = 1.f / (lG[(size_t)bh * SEQ + s] + lG[(size_t)(64 + bh) * SEQ + s]);
    union { uint4 v; u16 h[8]; } a, b, o;
    a.v = *(const uint4*)&pO[((size_t)bh * SEQ + s) * DK + chunk * 8];
    b.v = *(const uint4*)&pO[((size_t)(64 + bh) * SEQ + s) * DK + chunk * 8];
#pragma unroll
    for (int i = 0; i < 8; i++)
        o.h[i] = bfbits((bf2f(a.h[i]) + bf2f(b.h[i])) * inv);
    const int bb = bh >> 4, h = bh & 15;
    *(uint4*)&ctx[((size_t)(bb * SEQ + s)) * DMODEL + h * DK + chunk * 8] = o.v;
}

// ---------------- in-place LayerNorm ----------------
__global__ __launch_bounds__(256) void ln_inplace(float* __restrict__ y,
                                                  const float* __restrict__ gamma,
                                                  const float* __restrict__ beta) {
    const int row = blockIdx.x;
    float* p = y + (size_t)row * DMODEL;
    const int tid = threadIdx.x;
    float4 v = *(const float4*)(p + tid * 4);
    float s  = v.x + v.y + v.z + v.w;
    float sq = v.x * v.x + v.y * v.y + v.z * v.z + v.w * v.w;
#pragma unroll
    for (int m = 1; m < 64; m <<= 1) {
        s  += __shfl_xor(s, m);
        sq += __shfl_xor(sq, m);
    }
    __shared__ float rs[4], rq[4];
    if ((tid & 63) == 0) { rs[tid >> 6] = s; rq[tid >> 6] = sq; }
    __syncthreads();
    s  = rs[0] + rs[1] + rs[2] + rs[3];
    sq = rq[0] + rq[1] + rq[2] + rq[3];
    const float mean = s * (1.0f / 1024.0f);
    const float var  = sq * (1.0f / 1024.0f) - mean * mean;
    const float inv  = rsqrtf(var + 1e-5f);
    const int c = tid * 4;
    float4 g4 = *(const float4*)(gamma + c);
    float4 b4 = *(const float4*)(beta + c);
    float4 o;
    o.x = (v.x - mean) * inv * g4.x + b4.x;
    o.y = (v.y - mean) * inv * g4.y + b4.y;
    o.z = (v.z - mean) * inv * g4.z + b4.z;
    o.w = (v.w - mean) * inv * g4.w + b4.w;
    *(float4*)(p + c) = o;
}

extern "C" void kernel_launch(void* const* d_in, const int* in_sizes, int n_in,
                              void* d_out, int out_size, void* d_ws, size_t ws_size,
                              hipStream_t stream) {
    const float* x     = (const float*)d_in[0];
    const float* Wq    = (const float*)d_in[1];
    const float* bq    = (const float*)d_in[2];
    const float* Wk    = (const float*)d_in[3];
    const float* bk    = (const float*)d_in[4];
    const float* Wv    = (const float*)d_in[5];
    const float* bv    = (const float*)d_in[6];
    const float* Wo    = (const float*)d_in[7];
    const float* bo    = (const float*)d_in[8];
    const float* gamma = (const float*)d_in[9];
    const float* beta  = (const float*)d_in[10];
    float* out = (float*)d_out;

    u16* x_bf    = (u16*)d_ws;
    u16* Wqkv_bf = x_bf + (size_t)NROWS * DMODEL;
    u16* Wo_bf   = Wqkv_bf + (size_t)3072 * 1024;
    u16* Q_bf    = Wo_bf + (size_t)1024 * 1024;
    u16* K_bf    = Q_bf + (size_t)64 * SEQ * DK;
    u16* Vt_bf   = K_bf + (size_t)64 * SEQ * DK;
    u16* ctx_bf  = x_bf;                  // alias: x_bf dead after QKV GEMM
    u16* pO      = (u16*)d_out;           // 2x partial O (bf16) = 33.5 MB exact fit
    float* lG    = (float*)Wqkv_bf;       // 1 MB, Wqkv dead after gemm<0>

    cvt_f32_bf16<<<8192, 256, 0, stream>>>(x, x_bf, NROWS * DMODEL);
    cvt4_w<<<dim3(1024, 4), 256, 0, stream>>>(Wq, Wk, Wv, Wo,
                                              Wqkv_bf, Wqkv_bf + 1048576,
                                              Wqkv_bf + 2097152, Wo_bf);

    gemm_bt<0><<<dim3(64, 24), 256, 0, stream>>>(x_bf, Wqkv_bf,
                                                 bq, bk, bv, Q_bf, K_bf, Vt_bf,
                                                 nullptr, nullptr);
    attn<<<dim3(64, 8, 2), 512, 0, stream>>>(Q_bf, K_bf, Vt_bf, pO, lG);
    combine<<<4096, 256, 0, stream>>>(pO, lG, ctx_bf);
    gemm_bt<1><<<dim3(64, 8), 256, 0, stream>>>(ctx_bf, Wo_bf,
                                                bo, nullptr, nullptr,
                                                nullptr, nullptr, nullptr,
                                                x, out);
    ln_inplace<<<8192, 256, 0, stream>>>(out, gamma, beta);
}

// Round 11
// 204.663 us; speedup vs baseline: 1.0602x; 1.0602x over previous
//
#include <hip/hip_runtime.h>

// Fused MHA block: out = LayerNorm(x + MHA(x)).  B=4, S=2048, D=1024, H=16, dk=64.
// bf16 MFMA internal, fp32 I/O.
//
// Round 11 = Round 9 pipeline (204.6 us) + attn register-footprint fix:
//  R10 diagnosis: occupancy pinned at ~36% by TOTAL regs/wave (~150:
//  60 arch VGPR + ~90 AGPR accumulators) -> 3 waves/SIMD, grid-independent.
//  Fix: (a) sequential kpos-halves — one sacc/K-frag/P-frag set live at a
//  time (peak ~110-125 regs); (b) __launch_bounds__(512,4) caps at 128 regs
//  -> 4 waves/SIMD = 2 blocks/CU co-resident. Math unchanged (no-max softmax
//  is order-free). (c) cvt_x + cvt4_w merged into one launch.

#define SEQ 2048
#define DMODEL 1024
#define NH 16
#define DK 64
#define NROWS 8192  // B*S

typedef unsigned short u16;
typedef unsigned int u32;
typedef __bf16 bf16;
typedef bf16 bf16x8 __attribute__((ext_vector_type(8)));
typedef float f32x4 __attribute__((ext_vector_type(4)));
typedef float f32x16 __attribute__((ext_vector_type(16)));
typedef unsigned u32x2 __attribute__((ext_vector_type(2)));

__device__ inline u16 bfbits(float f) { return __builtin_bit_cast(u16, (bf16)f); }
__device__ inline u32 packbf2(float a, float b) {
    return (u32)bfbits(a) | ((u32)bfbits(b) << 16);
}

// Schraudolph exp2: s in (-120, 60); balanced rel error +-2.9%, cancels in
// softmax normalization. v_fma + v_cvt, full-rate VALU (no TRANS pipe).
__device__ inline float sexp2(float s) {
    return __builtin_bit_cast(float, (u32)(int)fmaf(s, 8388608.0f, 1064986823.0f));
}

// async global->LDS, 16B per lane; LDS dest = wave-uniform base + lane*16
__device__ inline void gload16(const u16* g, u16* l) {
    __builtin_amdgcn_global_load_lds(
        (const __attribute__((address_space(1))) u32*)g,
        (__attribute__((address_space(3))) u32*)l, 16, 0, 0);
}

// cross-half exchange (validated rounds 2-10)
__device__ inline void plswap(u32& a, u32& b) {
#if __has_builtin(__builtin_amdgcn_permlane32_swap)
    u32x2 r = __builtin_amdgcn_permlane32_swap(a, b, false, false);
    a = r[0]; b = r[1];
#else
    u32 xa = __shfl_xor(a, 32), xb = __shfl_xor(b, 32);
    int hi = (threadIdx.x & 63) >> 5;
    u32 na = hi ? xb : a;
    u32 nb = hi ? b : xa;
    a = na; b = nb;
#endif
}

// ---------------- fused fp32 -> bf16 convert: x (8192 blocks) + 4 weights ----------------
__global__ __launch_bounds__(256) void cvt_all(
    const float* __restrict__ x,  const float* __restrict__ w0,
    const float* __restrict__ w1, const float* __restrict__ w2,
    const float* __restrict__ w3,
    u16* __restrict__ xo, u16* __restrict__ o0, u16* __restrict__ o1,
    u16* __restrict__ o2, u16* __restrict__ o3) {
    const int b = blockIdx.x;
    const float* in;
    u16* out;
    int base;
    if (b < 8192) {
        in = x; out = xo; base = b << 10;
    } else {
        const int wsel = (b - 8192) >> 10;
        base = ((b - 8192) & 1023) << 10;
        switch (wsel) {
            case 0: in = w0; out = o0; break;
            case 1: in = w1; out = o1; break;
            case 2: in = w2; out = o2; break;
            default: in = w3; out = o3; break;
        }
    }
    const int i = base + threadIdx.x * 4;
    float4 v = *(const float4*)(in + i);
    ushort4 o;
    o.x = bfbits(v.x); o.y = bfbits(v.y); o.z = bfbits(v.z); o.w = bfbits(v.w);
    *(ushort4*)(out + i) = o;
}

// ---------------- GEMM: C[M,N] = A[M,K=1024] @ W[N,K]^T (+epilogue) ----------------
// 128x128 tile, BK=64, global_load_lds staging, XOR-swizzled via pre-swizzled source.
// EPI 0: QKV. Q/K quadrants: direct stores. V quadrant: LDS-transpose bounce.
template <int EPI>
__global__ __launch_bounds__(256) void gemm_bt(
    const u16* __restrict__ A, const u16* __restrict__ Bm,
    const float* __restrict__ bias0, const float* __restrict__ bias1,
    const float* __restrict__ bias2,
    u16* __restrict__ Qo, u16* __restrict__ Ko, u16* __restrict__ Vo,
    const float* __restrict__ xres, float* __restrict__ yout) {
    __shared__ __align__(16) u16 smem[16384];   // As = [0,8192), Bs = [8192,16384)
    u16* As = smem;
    u16* Bs = smem + 8192;

    const int tid  = threadIdx.x;
    const int lane = tid & 63;
    const int w    = tid >> 6;
    const int wr   = (w >> 1) * 64;
    const int wc   = (w & 1) * 64;
    const int l16  = lane & 15;
    const int lq   = lane >> 4;
    const int m0   = blockIdx.x * 128;
    const int n0   = blockIdx.y * 128;

    f32x4 acc[4][4];
#pragma unroll
    for (int m = 0; m < 4; m++)
#pragma unroll
        for (int n = 0; n < 4; n++) {
            f32x4 z = {0.f, 0.f, 0.f, 0.f};
            acc[m][n] = z;
        }

    const int l8r = lane >> 3;
    const int sch = (lane & 7) ^ l8r;
    const u16* a_g = A  + (size_t)(m0 + w * 32 + l8r) * 1024 + sch * 8;
    const u16* b_g = Bm + (size_t)(n0 + w * 32 + l8r) * 1024 + sch * 8;

    for (int k0 = 0; k0 < 1024; k0 += 64) {
        __syncthreads();
#pragma unroll
        for (int i = 0; i < 4; i++) {
            gload16(a_g + (size_t)i * 8192 + k0, As + (w * 32 + i * 8) * 64);
            gload16(b_g + (size_t)i * 8192 + k0, Bs + (w * 32 + i * 8) * 64);
        }
        __syncthreads();

#pragma unroll
        for (int kk = 0; kk < 2; kk++) {
            bf16x8 af[4], bfr[4];
#pragma unroll
            for (int m = 0; m < 4; m++)
                af[m] = *(const bf16x8*)&As[(wr + m * 16 + l16) * 64 +
                                            (((kk << 2) | lq) ^ (l16 & 7)) * 8];
#pragma unroll
            for (int n = 0; n < 4; n++)
                bfr[n] = *(const bf16x8*)&Bs[(wc + n * 16 + l16) * 64 +
                                             (((kk << 2) | lq) ^ (l16 & 7)) * 8];
            __builtin_amdgcn_s_setprio(1);
#pragma unroll
            for (int m = 0; m < 4; m++)
#pragma unroll
                for (int n = 0; n < 4; n++)
                    acc[m][n] = __builtin_amdgcn_mfma_f32_16x16x32_bf16(
                        af[m], bfr[n], acc[m][n], 0, 0, 0);
            __builtin_amdgcn_s_setprio(0);
        }
    }

    if (EPI == 0 && n0 >= 2048) {
        // ---- V quadrant: LDS-transpose bounce -> coalesced V^T stores ----
        const int e0 = n0 - 2048;
        __syncthreads();
#pragma unroll
        for (int m = 0; m < 4; m++)
#pragma unroll
            for (int n = 0; n < 4; n++) {
                const int col = wc + n * 16 + l16;       // local e
                const int row = wr + lq * 4 + m * 16;    // local s, 4-aligned
                const float bias = bias2[e0 + col];
                ushort4 pk;
                pk.x = bfbits(acc[m][n][0] + bias);
                pk.y = bfbits(acc[m][n][1] + bias);
                pk.z = bfbits(acc[m][n][2] + bias);
                pk.w = bfbits(acc[m][n][3] + bias);
                *(ushort4*)&smem[col * 128 + (row ^ ((col & 7) << 3))] = pk;
            }
        __syncthreads();
        const int b = m0 >> 11;
        const int sbase = m0 & 2047;
#pragma unroll
        for (int i = 0; i < 8; i++) {
            const int c = tid + 256 * i;
            const int col = c >> 4;
            const int s0 = (c & 15) * 8;
            uint4 val = *(const uint4*)&smem[col * 128 + (s0 ^ ((col & 7) << 3))];
            const int eg = e0 + col;
            const int bh = b * NH + (eg >> 6);
            *(uint4*)&Vo[((size_t)bh * DK + (eg & 63)) * SEQ + sbase + s0] = val;
        }
        return;
    }

    const int rbase = m0 + wr + lq * 4;
    const int cbase = n0 + wc + l16;
#pragma unroll
    for (int m = 0; m < 4; m++)
#pragma unroll
        for (int n = 0; n < 4; n++) {
            const int col = cbase + n * 16;
#pragma unroll
            for (int r = 0; r < 4; r++) {
                const int row = rbase + m * 16 + r;
                float v = acc[m][n][r];
                if (EPI == 0) {
                    const int which = col >> 10;   // 0=Q, 1=K (V handled above)
                    const int e = col & 1023;
                    v += (which == 0) ? bias0[e] : bias1[e];
                    if (which == 0) v *= 0.18033688011112042f;  // 1/sqrt(dk) * log2(e)
                    const int h = e >> 6, d = e & 63;
                    const int b = row >> 11, s = row & 2047;
                    const int bh = b * NH + h;
                    if (which == 0)
                        Qo[((size_t)bh * SEQ + s) * DK + d] = bfbits(v);
                    else
                        Ko[((size_t)bh * SEQ + s) * DK + d] = bfbits(v);
                } else {
                    v += bias0[col] + xres[(size_t)row * DMODEL + col];
                    yout[(size_t)row * DMODEL + col] = v;
                }
            }
        }
}

// ---------------- flash attention, swapped-QK^T, KVBLK=64, sequential halves ----------------
// grid (B*H, S/256), 512 thr = 8 waves; wave w owns q rows [q0, q0+32).
// Per tile, kpos halves [0,32) and [32,64) processed SEQUENTIALLY so only one
// sacc + one K-frag set + one P-frag pair is live at a time; launch bound
// (512,4) caps regs at 128/wave -> 4 waves/SIMD.
__global__ __launch_bounds__(512, 4) void attn(const u16* __restrict__ Qb,
                                               const u16* __restrict__ Kb,
                                               const u16* __restrict__ Vtb,
                                               u16* __restrict__ ctx) {
    // K bufs 2x[64][64] elems 0..8191; V^T bufs 2x[64][64] elems 8192..16383.
    __shared__ __align__(16) u16 smem[16384];

    const int tid  = threadIdx.x;
    const int lane = tid & 63;
    const int w    = tid >> 6;
    const int q    = lane & 31;
    const int hi   = lane >> 5;
    const int bh   = blockIdx.x;
    const int q0   = blockIdx.y * 256 + w * 32;

    const u16* qp = Qb + ((size_t)bh * SEQ + q0 + q) * DK + hi * 8;
    bf16x8 qf0 = *(const bf16x8*)(qp);
    bf16x8 qf1 = *(const bf16x8*)(qp + 16);
    bf16x8 qf2 = *(const bf16x8*)(qp + 32);
    bf16x8 qf3 = *(const bf16x8*)(qp + 48);

    // staging: wave w stages K rows [w*8, w*8+8) and V^T rows [w*8, w*8+8).
    const int l8r = lane >> 3;
    const int sch = (lane & 7) ^ l8r;
    const u16* kg = Kb  + ((size_t)bh * SEQ + w * 8 + l8r) * 64 + sch * 8;   // +4096/tile
    const u16* vg = Vtb + ((size_t)bh * DK  + w * 8 + l8r) * SEQ + sch * 8;  // +64/tile
    u16* kl = smem + w * 512;
    u16* vl = smem + 8192 + w * 512;

    f32x16 oacc0, oacc1;
#pragma unroll
    for (int r = 0; r < 16; r++) { oacc0[r] = 0.f; oacc1[r] = 0.f; }
    f32x16 fzero;
#pragma unroll
    for (int r = 0; r < 16; r++) fzero[r] = 0.f;
    float l_ = 0.f;

    gload16(kg, kl);
    gload16(vg, vl);
    __syncthreads();

    for (int t = 0; t < SEQ / 64; t++) {
        if (t < SEQ / 64 - 1) {
            gload16(kg + (size_t)(t + 1) * 4096, kl + ((t + 1) & 1) * 4096);
            gload16(vg + (size_t)(t + 1) * 64,  vl + ((t + 1) & 1) * 4096);
        }
        const u16* Kl = smem + (t & 1) * 4096;
        const u16* Vl = smem + 8192 + (t & 1) * 4096;

#pragma unroll
        for (int half = 0; half < 2; half++) {
            const int kr = q + half * 32;      // K row (kpos within tile)
            // ---- QK^T for this 32-kpos half ----
            bf16x8 ka = *(const bf16x8*)&Kl[kr * 64 + ((0 | hi) ^ (q & 7)) * 8];
            bf16x8 kb = *(const bf16x8*)&Kl[kr * 64 + ((2 | hi) ^ (q & 7)) * 8];
            bf16x8 kc = *(const bf16x8*)&Kl[kr * 64 + ((4 | hi) ^ (q & 7)) * 8];
            bf16x8 kd = *(const bf16x8*)&Kl[kr * 64 + ((6 | hi) ^ (q & 7)) * 8];
            __builtin_amdgcn_s_setprio(1);
            f32x16 sacc = __builtin_amdgcn_mfma_f32_32x32x16_bf16(ka, qf0, fzero, 0, 0, 0);
            sacc = __builtin_amdgcn_mfma_f32_32x32x16_bf16(kb, qf1, sacc, 0, 0, 0);
            sacc = __builtin_amdgcn_mfma_f32_32x32x16_bf16(kc, qf2, sacc, 0, 0, 0);
            sacc = __builtin_amdgcn_mfma_f32_32x32x16_bf16(kd, qf3, sacc, 0, 0, 0);
            __builtin_amdgcn_s_setprio(0);

            // ---- no-max softmax via Schraudolph exp2 ----
#pragma unroll
            for (int r = 0; r < 16; r++) sacc[r] = sexp2(sacc[r]);
            {
                float s0 = ((sacc[0] + sacc[1]) + (sacc[2] + sacc[3])) +
                           ((sacc[4] + sacc[5]) + (sacc[6] + sacc[7]));
                float s1 = ((sacc[8] + sacc[9]) + (sacc[10] + sacc[11])) +
                           ((sacc[12] + sacc[13]) + (sacc[14] + sacc[15]));
                l_ += s0 + s1;
            }

            // ---- pack P to bf16 + permlane exchange -> P^T B-frags ----
            u32 wa[8];
#pragma unroll
            for (int i = 0; i < 8; i++) wa[i] = packbf2(sacc[2 * i], sacc[2 * i + 1]);
            plswap(wa[0], wa[2]); plswap(wa[1], wa[3]);
            plswap(wa[4], wa[6]); plswap(wa[5], wa[7]);
            union { u32 u[4]; bf16x8 v; } pf0, pf1;
            pf0.u[0] = wa[0]; pf0.u[1] = wa[1]; pf0.u[2] = wa[2]; pf0.u[3] = wa[3];
            pf1.u[0] = wa[4]; pf1.u[1] = wa[5]; pf1.u[2] = wa[6]; pf1.u[3] = wa[7];

            // ---- O^T += V^T . P^T (kpos slots half*2, half*2+1) ----
            const int c0 = ((half * 2 + 0) * 2) | hi;   // V chunk for kpos slot
            const int c1 = ((half * 2 + 1) * 2) | hi;
            bf16x8 va = *(const bf16x8*)&Vl[(q)      * 64 + (c0 ^ (q & 7)) * 8];
            bf16x8 vb = *(const bf16x8*)&Vl[(q)      * 64 + (c1 ^ (q & 7)) * 8];
            bf16x8 vc = *(const bf16x8*)&Vl[(q + 32) * 64 + (c0 ^ (q & 7)) * 8];
            bf16x8 vd = *(const bf16x8*)&Vl[(q + 32) * 64 + (c1 ^ (q & 7)) * 8];
            __builtin_amdgcn_s_setprio(1);
            oacc0 = __builtin_amdgcn_mfma_f32_32x32x16_bf16(va, pf0.v, oacc0, 0, 0, 0);
            oacc1 = __builtin_amdgcn_mfma_f32_32x32x16_bf16(vc, pf0.v, oacc1, 0, 0, 0);
            oacc0 = __builtin_amdgcn_mfma_f32_32x32x16_bf16(vb, pf1.v, oacc0, 0, 0, 0);
            oacc1 = __builtin_amdgcn_mfma_f32_32x32x16_bf16(vd, pf1.v, oacc1, 0, 0, 0);
            __builtin_amdgcn_s_setprio(0);
        }

        __syncthreads();
    }

    // ---- merge half-lane l partials once, then epilogue ----
    const float lfull = l_ + __shfl_xor(l_, 32);
    const float invl = 1.f / lfull;
    const int wbase = w * 2048;
#pragma unroll
    for (int r = 0; r < 16; r++) {
        const int dk0 = (r & 3) + 8 * (r >> 2) + 4 * hi;
        const int dk1 = 32 + dk0;
        smem[wbase + q * 64 + (((dk0 >> 3) ^ (q & 7)) << 3) + (dk0 & 7)] = bfbits(oacc0[r] * invl);
        smem[wbase + q * 64 + (((dk1 >> 3) ^ (q & 7)) << 3) + (dk1 & 7)] = bfbits(oacc1[r] * invl);
    }
    __syncthreads();
    const int b = bh >> 4, h = bh & 15;
    const int r4 = lane >> 1;
    const int cc = (lane & 1) * 4;
#pragma unroll
    for (int c = 0; c < 4; c++) {
        const int chunk = cc + c;
        uint4 val = *(const uint4*)&smem[wbase + r4 * 64 + ((chunk ^ (r4 & 7)) << 3)];
        *(uint4*)&ctx[((size_t)(b * SEQ + q0 + r4)) * DMODEL + h * DK + chunk * 8] = val;
    }
}

// ---------------- in-place LayerNorm ----------------
__global__ __launch_bounds__(256) void ln_inplace(float* __restrict__ y,
                                                  const float* __restrict__ gamma,
                                                  const float* __restrict__ beta) {
    const int row = blockIdx.x;
    float* p = y + (size_t)row * DMODEL;
    const int tid = threadIdx.x;
    float4 v = *(const float4*)(p + tid * 4);
    float s  = v.x + v.y + v.z + v.w;
    float sq = v.x * v.x + v.y * v.y + v.z * v.z + v.w * v.w;
#pragma unroll
    for (int m = 1; m < 64; m <<= 1) {
        s  += __shfl_xor(s, m);
        sq += __shfl_xor(sq, m);
    }
    __shared__ float rs[4], rq[4];
    if ((tid & 63) == 0) { rs[tid >> 6] = s; rq[tid >> 6] = sq; }
    __syncthreads();
    s  = rs[0] + rs[1] + rs[2] + rs[3];
    sq = rq[0] + rq[1] + rq[2] + rq[3];
    const float mean = s * (1.0f / 1024.0f);
    const float var  = sq * (1.0f / 1024.0f) - mean * mean;
    const float inv  = rsqrtf(var + 1e-5f);
    const int c = tid * 4;
    float4 g4 = *(const float4*)(gamma + c);
    float4 b4 = *(const float4*)(beta + c);
    float4 o;
    o.x = (v.x - mean) * inv * g4.x + b4.x;
    o.y = (v.y - mean) * inv * g4.y + b4.y;
    o.z = (v.z - mean) * inv * g4.z + b4.z;
    o.w = (v.w - mean) * inv * g4.w + b4.w;
    *(float4*)(p + c) = o;
}

extern "C" void kernel_launch(void* const* d_in, const int* in_sizes, int n_in,
                              void* d_out, int out_size, void* d_ws, size_t ws_size,
                              hipStream_t stream) {
    const float* x     = (const float*)d_in[0];
    const float* Wq    = (const float*)d_in[1];
    const float* bq    = (const float*)d_in[2];
    const float* Wk    = (const float*)d_in[3];
    const float* bk    = (const float*)d_in[4];
    const float* Wv    = (const float*)d_in[5];
    const float* bv    = (const float*)d_in[6];
    const float* Wo    = (const float*)d_in[7];
    const float* bo    = (const float*)d_in[8];
    const float* gamma = (const float*)d_in[9];
    const float* beta  = (const float*)d_in[10];
    float* out = (float*)d_out;

    u16* x_bf    = (u16*)d_ws;
    u16* Wqkv_bf = x_bf + (size_t)NROWS * DMODEL;
    u16* Wo_bf   = Wqkv_bf + (size_t)3072 * 1024;
    u16* Q_bf    = Wo_bf + (size_t)1024 * 1024;
    u16* K_bf    = Q_bf + (size_t)64 * SEQ * DK;
    u16* Vt_bf   = K_bf + (size_t)64 * SEQ * DK;
    u16* ctx_bf  = x_bf;  // alias: x_bf dead after QKV GEMM

    cvt_all<<<12288, 256, 0, stream>>>(x, Wq, Wk, Wv, Wo,
                                       x_bf, Wqkv_bf, Wqkv_bf + 1048576,
                                       Wqkv_bf + 2097152, Wo_bf);

    gemm_bt<0><<<dim3(64, 24), 256, 0, stream>>>(x_bf, Wqkv_bf,
                                                 bq, bk, bv, Q_bf, K_bf, Vt_bf,
                                                 nullptr, nullptr);
    attn<<<dim3(64, 8), 512, 0, stream>>>(Q_bf, K_bf, Vt_bf, ctx_bf);
    gemm_bt<1><<<dim3(64, 8), 256, 0, stream>>>(ctx_bf, Wo_bf,
                                                bo, nullptr, nullptr,
                                                nullptr, nullptr, nullptr,
                                                x, out);
    ln_inplace<<<8192, 256, 0, stream>>>(out, gamma, beta);
}

// Round 12
// 200.093 us; speedup vs baseline: 1.0845x; 1.0228x over previous
//
#include <hip/hip_runtime.h>

// Fused MHA block: out = LayerNorm(x + MHA(x)).  B=4, S=2048, D=1024, H=16, dk=64.
// bf16 MFMA internal, fp32 I/O.
//
// Round 12: attn reverted to R9 body (94us best). gemm<0> rewritten as
// gemm_qkv: 128x256 tile, BK=64, 8 waves (2x4), counted-vmcnt pipeline
// (T3+T4): 2 LDS buffers (96KB), prefetch depth 2 K-tiles, s_waitcnt vmcnt(6)
// in-loop (never 0), raw s_barrier (no compiler drain). Grid 64x12=768 blocks
// = exactly 3/CU, no tail. gemm<1> = old 128x128 kernel (EPI=1 path only).

#define SEQ 2048
#define DMODEL 1024
#define NH 16
#define DK 64
#define NROWS 8192  // B*S

typedef unsigned short u16;
typedef unsigned int u32;
typedef __bf16 bf16;
typedef bf16 bf16x8 __attribute__((ext_vector_type(8)));
typedef float f32x4 __attribute__((ext_vector_type(4)));
typedef float f32x16 __attribute__((ext_vector_type(16)));
typedef unsigned u32x2 __attribute__((ext_vector_type(2)));

__device__ inline u16 bfbits(float f) { return __builtin_bit_cast(u16, (bf16)f); }
__device__ inline u32 packbf2(float a, float b) {
    return (u32)bfbits(a) | ((u32)bfbits(b) << 16);
}

// Schraudolph exp2 (validated R8/R9): full-rate VALU, error cancels in norm.
__device__ inline float sexp2(float s) {
    return __builtin_bit_cast(float, (u32)(int)fmaf(s, 8388608.0f, 1064986823.0f));
}

// async global->LDS, 16B per lane; LDS dest = wave-uniform base + lane*16
__device__ inline void gload16(const u16* g, u16* l) {
    __builtin_amdgcn_global_load_lds(
        (const __attribute__((address_space(1))) u32*)g,
        (__attribute__((address_space(3))) u32*)l, 16, 0, 0);
}

// cross-half exchange (validated rounds 2-11)
__device__ inline void plswap(u32& a, u32& b) {
#if __has_builtin(__builtin_amdgcn_permlane32_swap)
    u32x2 r = __builtin_amdgcn_permlane32_swap(a, b, false, false);
    a = r[0]; b = r[1];
#else
    u32 xa = __shfl_xor(a, 32), xb = __shfl_xor(b, 32);
    int hi = (threadIdx.x & 63) >> 5;
    u32 na = hi ? xb : a;
    u32 nb = hi ? b : xa;
    a = na; b = nb;
#endif
}

// ---------------- fused fp32 -> bf16 convert: x + 4 weights ----------------
__global__ __launch_bounds__(256) void cvt_all(
    const float* __restrict__ x,  const float* __restrict__ w0,
    const float* __restrict__ w1, const float* __restrict__ w2,
    const float* __restrict__ w3,
    u16* __restrict__ xo, u16* __restrict__ o0, u16* __restrict__ o1,
    u16* __restrict__ o2, u16* __restrict__ o3) {
    const int b = blockIdx.x;
    const float* in;
    u16* out;
    int base;
    if (b < 8192) {
        in = x; out = xo; base = b << 10;
    } else {
        const int wsel = (b - 8192) >> 10;
        base = ((b - 8192) & 1023) << 10;
        switch (wsel) {
            case 0: in = w0; out = o0; break;
            case 1: in = w1; out = o1; break;
            case 2: in = w2; out = o2; break;
            default: in = w3; out = o3; break;
        }
    }
    const int i = base + threadIdx.x * 4;
    float4 v = *(const float4*)(in + i);
    ushort4 o;
    o.x = bfbits(v.x); o.y = bfbits(v.y); o.z = bfbits(v.z); o.w = bfbits(v.w);
    *(ushort4*)(out + i) = o;
}

// ---------------- QKV GEMM: counted-vmcnt pipeline ----------------
// C[8192,3072] = x_bf[8192,1024] @ Wqkv[3072,1024]^T. BM=128 BN=256 BK=64,
// 512 thr = 8 waves (wm=w>>2 in {0,1}: rows wm*64; wn=w&3: cols wn*64).
// LDS: As 2x[128][64] (32KB) + Bs 2x[256][64] (64KB) = 96KB -> 1 block/CU.
// Pipeline: prefetch depth 2 tiles; per-wave 6 loads/tile; vmcnt(6) in-loop.
__global__ __launch_bounds__(512) void gemm_qkv(
    const u16* __restrict__ A, const u16* __restrict__ Bm,
    const float* __restrict__ bq, const float* __restrict__ bk,
    const float* __restrict__ bv,
    u16* __restrict__ Qo, u16* __restrict__ Ko, u16* __restrict__ Vo) {
    __shared__ __align__(16) u16 smem[49152];   // As[2]@0, Bs[2]@16384

    const int tid  = threadIdx.x;
    const int lane = tid & 63;
    const int w    = tid >> 6;       // 0..7
    const int wr   = (w >> 2) * 64;  // row base (128 rows / 2)
    const int wc   = (w & 3) * 64;   // col base (256 cols / 4)
    const int l16  = lane & 15;
    const int lq   = lane >> 4;
    const int m0   = blockIdx.x * 128;
    const int n0   = blockIdx.y * 256;

    f32x4 acc[4][4];
#pragma unroll
    for (int m = 0; m < 4; m++)
#pragma unroll
        for (int n = 0; n < 4; n++) {
            f32x4 z = {0.f, 0.f, 0.f, 0.f};
            acc[m][n] = z;
        }

    // staging: per issue, wave w stages 8 rows (lane: row-in-8 = l>>3,
    // pre-swizzled source chunk = (l&7)^(l>>3)). A: 2 issues (128 rows),
    // B: 4 issues (256 rows). 6 issues per K-tile per wave.
    const int l8r = lane >> 3;
    const int sch = (lane & 7) ^ l8r;
    const u16* a_g = A  + (size_t)(m0 + w * 8 + l8r) * 1024 + sch * 8;
    const u16* b_g = Bm + (size_t)(n0 + w * 8 + l8r) * 1024 + sch * 8;
    u16* asd = smem + (w * 8) * 64;          // + i*4096 per issue, + c*8192
    u16* bsd = smem + 16384 + (w * 8) * 64;  // + i*4096 per issue, + c*16384

#define STAGE(kt, c) do {                                                  \
        gload16(a_g + (kt) * 64,          asd + (c) * 8192);               \
        gload16(a_g + 65536 + (kt) * 64,  asd + (c) * 8192 + 4096);        \
        gload16(b_g + (kt) * 64,          bsd + (c) * 16384);              \
        gload16(b_g + 65536 + (kt) * 64,  bsd + (c) * 16384 + 4096);       \
        gload16(b_g + 131072 + (kt) * 64, bsd + (c) * 16384 + 8192);       \
        gload16(b_g + 196608 + (kt) * 64, bsd + (c) * 16384 + 12288);      \
    } while (0)

    STAGE(0, 0);
    STAGE(1, 1);

    for (int kt = 0; kt < 16; kt++) {
        const int cur = kt & 1;
        // counted wait: outstanding = T_kt remnants + T_{kt+1}(6 newest);
        // vmcnt(6) => T_kt fully landed, T_{kt+1} stays in flight.
        if (kt < 15) asm volatile("s_waitcnt vmcnt(6)" ::: "memory");
        else         asm volatile("s_waitcnt vmcnt(0)" ::: "memory");
        __builtin_amdgcn_s_barrier();

        const u16* Asl = smem + cur * 8192;
        const u16* Bsl = smem + 16384 + cur * 16384;
#pragma unroll
        for (int kk = 0; kk < 2; kk++) {
            bf16x8 af[4], bfr[4];
#pragma unroll
            for (int m = 0; m < 4; m++)
                af[m] = *(const bf16x8*)&Asl[(wr + m * 16 + l16) * 64 +
                                             (((kk << 2) | lq) ^ (l16 & 7)) * 8];
#pragma unroll
            for (int n = 0; n < 4; n++)
                bfr[n] = *(const bf16x8*)&Bsl[(wc + n * 16 + l16) * 64 +
                                              (((kk << 2) | lq) ^ (l16 & 7)) * 8];
            __builtin_amdgcn_s_setprio(1);
#pragma unroll
            for (int m = 0; m < 4; m++)
#pragma unroll
                for (int n = 0; n < 4; n++)
                    acc[m][n] = __builtin_amdgcn_mfma_f32_16x16x32_bf16(
                        af[m], bfr[n], acc[m][n], 0, 0, 0);
            __builtin_amdgcn_s_setprio(0);
        }
        __builtin_amdgcn_s_barrier();    // all waves done reading buf[cur]
        if (kt < 14) STAGE(kt + 2, cur); // overwrite buf[cur] with tile kt+2
    }
#undef STAGE

    if (n0 >= 2048) {
        // ---- V quadrant: LDS-transpose bounce (256 cols x 128 rows) ----
        const int e0 = n0 - 2048;
#pragma unroll
        for (int m = 0; m < 4; m++)
#pragma unroll
            for (int n = 0; n < 4; n++) {
                const int col = wc + n * 16 + l16;       // 0..255 local e
                const int row = wr + lq * 4 + m * 16;    // 0..127 local s
                const float bias = bv[e0 + col];
                ushort4 pk;
                pk.x = bfbits(acc[m][n][0] + bias);
                pk.y = bfbits(acc[m][n][1] + bias);
                pk.z = bfbits(acc[m][n][2] + bias);
                pk.w = bfbits(acc[m][n][3] + bias);
                *(ushort4*)&smem[col * 128 + (row ^ ((col & 7) << 3))] = pk;
            }
        __syncthreads();
        const int b = m0 >> 11;
        const int sbase = m0 & 2047;
#pragma unroll
        for (int i = 0; i < 8; i++) {
            const int c = tid + 512 * i;    // 0..4095
            const int col = c >> 4;         // 0..255
            const int s0 = (c & 15) * 8;    // 0..120
            uint4 val = *(const uint4*)&smem[col * 128 + (s0 ^ ((col & 7) << 3))];
            const int eg = e0 + col;
            const int bh = b * NH + (eg >> 6);
            *(uint4*)&Vo[((size_t)bh * DK + (eg & 63)) * SEQ + sbase + s0] = val;
        }
        return;
    }

    // ---- Q/K quadrants: direct stores ----
    const int which = n0 >> 10;              // 0 = Q, 1 = K (block-uniform)
    const int rbase = m0 + wr + lq * 4;
#pragma unroll
    for (int m = 0; m < 4; m++)
#pragma unroll
        for (int n = 0; n < 4; n++) {
            const int e = ((n0 & 1023) + wc + n * 16 + l16);
            const float bias = (which == 0) ? bq[e] : bk[e];
            const int h = e >> 6, d = e & 63;
#pragma unroll
            for (int r = 0; r < 4; r++) {
                const int row = rbase + m * 16 + r;
                float v = acc[m][n][r] + bias;
                if (which == 0) v *= 0.18033688011112042f;  // 1/sqrt(dk)*log2(e)
                const int b = row >> 11, s = row & 2047;
                const int bh = b * NH + h;
                if (which == 0)
                    Qo[((size_t)bh * SEQ + s) * DK + d] = bfbits(v);
                else
                    Ko[((size_t)bh * SEQ + s) * DK + d] = bfbits(v);
            }
        }
}

// ---------------- O-projection GEMM (old 128x128 structure, EPI=1) ----------------
__global__ __launch_bounds__(256) void gemm_o(
    const u16* __restrict__ A, const u16* __restrict__ Bm,
    const float* __restrict__ bias,
    const float* __restrict__ xres, float* __restrict__ yout) {
    __shared__ __align__(16) u16 smem[16384];
    u16* As = smem;
    u16* Bs = smem + 8192;

    const int tid  = threadIdx.x;
    const int lane = tid & 63;
    const int w    = tid >> 6;
    const int wr   = (w >> 1) * 64;
    const int wc   = (w & 1) * 64;
    const int l16  = lane & 15;
    const int lq   = lane >> 4;
    const int m0   = blockIdx.x * 128;
    const int n0   = blockIdx.y * 128;

    f32x4 acc[4][4];
#pragma unroll
    for (int m = 0; m < 4; m++)
#pragma unroll
        for (int n = 0; n < 4; n++) {
            f32x4 z = {0.f, 0.f, 0.f, 0.f};
            acc[m][n] = z;
        }

    const int l8r = lane >> 3;
    const int sch = (lane & 7) ^ l8r;
    const u16* a_g = A  + (size_t)(m0 + w * 32 + l8r) * 1024 + sch * 8;
    const u16* b_g = Bm + (size_t)(n0 + w * 32 + l8r) * 1024 + sch * 8;

    for (int k0 = 0; k0 < 1024; k0 += 64) {
        __syncthreads();
#pragma unroll
        for (int i = 0; i < 4; i++) {
            gload16(a_g + (size_t)i * 8192 + k0, As + (w * 32 + i * 8) * 64);
            gload16(b_g + (size_t)i * 8192 + k0, Bs + (w * 32 + i * 8) * 64);
        }
        __syncthreads();

#pragma unroll
        for (int kk = 0; kk < 2; kk++) {
            bf16x8 af[4], bfr[4];
#pragma unroll
            for (int m = 0; m < 4; m++)
                af[m] = *(const bf16x8*)&As[(wr + m * 16 + l16) * 64 +
                                            (((kk << 2) | lq) ^ (l16 & 7)) * 8];
#pragma unroll
            for (int n = 0; n < 4; n++)
                bfr[n] = *(const bf16x8*)&Bs[(wc + n * 16 + l16) * 64 +
                                             (((kk << 2) | lq) ^ (l16 & 7)) * 8];
            __builtin_amdgcn_s_setprio(1);
#pragma unroll
            for (int m = 0; m < 4; m++)
#pragma unroll
                for (int n = 0; n < 4; n++)
                    acc[m][n] = __builtin_amdgcn_mfma_f32_16x16x32_bf16(
                        af[m], bfr[n], acc[m][n], 0, 0, 0);
            __builtin_amdgcn_s_setprio(0);
        }
    }

    const int rbase = m0 + wr + lq * 4;
    const int cbase = n0 + wc + l16;
#pragma unroll
    for (int m = 0; m < 4; m++)
#pragma unroll
        for (int n = 0; n < 4; n++) {
            const int col = cbase + n * 16;
#pragma unroll
            for (int r = 0; r < 4; r++) {
                const int row = rbase + m * 16 + r;
                float v = acc[m][n][r] + bias[col] + xres[(size_t)row * DMODEL + col];
                yout[(size_t)row * DMODEL + col] = v;
            }
        }
}

// ---------------- flash attention (R9 body: 94us) ----------------
__global__ __launch_bounds__(512) void attn(const u16* __restrict__ Qb,
                                            const u16* __restrict__ Kb,
                                            const u16* __restrict__ Vtb,
                                            u16* __restrict__ ctx) {
    __shared__ __align__(16) u16 smem[16384];

    const int tid  = threadIdx.x;
    const int lane = tid & 63;
    const int w    = tid >> 6;
    const int q    = lane & 31;
    const int hi   = lane >> 5;
    const int bh   = blockIdx.x;
    const int q0   = blockIdx.y * 256 + w * 32;

    const u16* qp = Qb + ((size_t)bh * SEQ + q0 + q) * DK + hi * 8;
    bf16x8 qf0 = *(const bf16x8*)(qp);
    bf16x8 qf1 = *(const bf16x8*)(qp + 16);
    bf16x8 qf2 = *(const bf16x8*)(qp + 32);
    bf16x8 qf3 = *(const bf16x8*)(qp + 48);

    const int l8r = lane >> 3;
    const int sch = (lane & 7) ^ l8r;
    const u16* kg = Kb  + ((size_t)bh * SEQ + w * 8 + l8r) * 64 + sch * 8;
    const u16* vg = Vtb + ((size_t)bh * DK  + w * 8 + l8r) * SEQ + sch * 8;
    u16* kl = smem + w * 512;
    u16* vl = smem + 8192 + w * 512;

    f32x16 oacc0, oacc1;
#pragma unroll
    for (int r = 0; r < 16; r++) { oacc0[r] = 0.f; oacc1[r] = 0.f; }
    f32x16 fzero;
#pragma unroll
    for (int r = 0; r < 16; r++) fzero[r] = 0.f;
    float l_ = 0.f;

    gload16(kg, kl);
    gload16(vg, vl);
    __syncthreads();

    for (int t = 0; t < SEQ / 64; t++) {
        if (t < SEQ / 64 - 1) {
            gload16(kg + (size_t)(t + 1) * 4096, kl + ((t + 1) & 1) * 4096);
            gload16(vg + (size_t)(t + 1) * 64,  vl + ((t + 1) & 1) * 4096);
        }
        const u16* Kl = smem + (t & 1) * 4096;
        const u16* Vl = smem + 8192 + (t & 1) * 4096;

        f32x16 sacc0, sacc1;
        {
            bf16x8 k00 = *(const bf16x8*)&Kl[(q)      * 64 + ((0 | hi) ^ (q & 7)) * 8];
            bf16x8 k01 = *(const bf16x8*)&Kl[(q)      * 64 + ((2 | hi) ^ (q & 7)) * 8];
            bf16x8 k02 = *(const bf16x8*)&Kl[(q)      * 64 + ((4 | hi) ^ (q & 7)) * 8];
            bf16x8 k03 = *(const bf16x8*)&Kl[(q)      * 64 + ((6 | hi) ^ (q & 7)) * 8];
            bf16x8 k10 = *(const bf16x8*)&Kl[(q + 32) * 64 + ((0 | hi) ^ (q & 7)) * 8];
            bf16x8 k11 = *(const bf16x8*)&Kl[(q + 32) * 64 + ((2 | hi) ^ (q & 7)) * 8];
            bf16x8 k12 = *(const bf16x8*)&Kl[(q + 32) * 64 + ((4 | hi) ^ (q & 7)) * 8];
            bf16x8 k13 = *(const bf16x8*)&Kl[(q + 32) * 64 + ((6 | hi) ^ (q & 7)) * 8];
            __builtin_amdgcn_s_setprio(1);
            sacc0 = __builtin_amdgcn_mfma_f32_32x32x16_bf16(k00, qf0, fzero, 0, 0, 0);
            sacc1 = __builtin_amdgcn_mfma_f32_32x32x16_bf16(k10, qf0, fzero, 0, 0, 0);
            sacc0 = __builtin_amdgcn_mfma_f32_32x32x16_bf16(k01, qf1, sacc0, 0, 0, 0);
            sacc1 = __builtin_amdgcn_mfma_f32_32x32x16_bf16(k11, qf1, sacc1, 0, 0, 0);
            sacc0 = __builtin_amdgcn_mfma_f32_32x32x16_bf16(k02, qf2, sacc0, 0, 0, 0);
            sacc1 = __builtin_amdgcn_mfma_f32_32x32x16_bf16(k12, qf2, sacc1, 0, 0, 0);
            sacc0 = __builtin_amdgcn_mfma_f32_32x32x16_bf16(k03, qf3, sacc0, 0, 0, 0);
            sacc1 = __builtin_amdgcn_mfma_f32_32x32x16_bf16(k13, qf3, sacc1, 0, 0, 0);
            __builtin_amdgcn_s_setprio(0);
        }

#pragma unroll
        for (int r = 0; r < 16; r++) sacc0[r] = sexp2(sacc0[r]);
#pragma unroll
        for (int r = 0; r < 16; r++) sacc1[r] = sexp2(sacc1[r]);
        {
            float s0 = ((sacc0[0] + sacc0[1]) + (sacc0[2] + sacc0[3])) +
                       ((sacc0[4] + sacc0[5]) + (sacc0[6] + sacc0[7]));
            float s1 = ((sacc0[8] + sacc0[9]) + (sacc0[10] + sacc0[11])) +
                       ((sacc0[12] + sacc0[13]) + (sacc0[14] + sacc0[15]));
            float s2 = ((sacc1[0] + sacc1[1]) + (sacc1[2] + sacc1[3])) +
                       ((sacc1[4] + sacc1[5]) + (sacc1[6] + sacc1[7]));
            float s3 = ((sacc1[8] + sacc1[9]) + (sacc1[10] + sacc1[11])) +
                       ((sacc1[12] + sacc1[13]) + (sacc1[14] + sacc1[15]));
            l_ += (s0 + s1) + (s2 + s3);
        }

        u32 wa[8], wb[8];
#pragma unroll
        for (int i = 0; i < 8; i++) wa[i] = packbf2(sacc0[2 * i], sacc0[2 * i + 1]);
#pragma unroll
        for (int i = 0; i < 8; i++) wb[i] = packbf2(sacc1[2 * i], sacc1[2 * i + 1]);
        plswap(wa[0], wa[2]); plswap(wa[1], wa[3]);
        plswap(wa[4], wa[6]); plswap(wa[5], wa[7]);
        plswap(wb[0], wb[2]); plswap(wb[1], wb[3]);
        plswap(wb[4], wb[6]); plswap(wb[5], wb[7]);
        union { u32 u[4]; bf16x8 v; } pf0, pf1, pf2, pf3;
        pf0.u[0] = wa[0]; pf0.u[1] = wa[1]; pf0.u[2] = wa[2]; pf0.u[3] = wa[3];
        pf1.u[0] = wa[4]; pf1.u[1] = wa[5]; pf1.u[2] = wa[6]; pf1.u[3] = wa[7];
        pf2.u[0] = wb[0]; pf2.u[1] = wb[1]; pf2.u[2] = wb[2]; pf2.u[3] = wb[3];
        pf3.u[0] = wb[4]; pf3.u[1] = wb[5]; pf3.u[2] = wb[6]; pf3.u[3] = wb[7];

        {
            bf16x8 v00 = *(const bf16x8*)&Vl[(q)      * 64 + ((0 | hi) ^ (q & 7)) * 8];
            bf16x8 v01 = *(const bf16x8*)&Vl[(q)      * 64 + ((2 | hi) ^ (q & 7)) * 8];
            bf16x8 v02 = *(const bf16x8*)&Vl[(q)      * 64 + ((4 | hi) ^ (q & 7)) * 8];
            bf16x8 v03 = *(const bf16x8*)&Vl[(q)      * 64 + ((6 | hi) ^ (q & 7)) * 8];
            bf16x8 v10 = *(const bf16x8*)&Vl[(q + 32) * 64 + ((0 | hi) ^ (q & 7)) * 8];
            bf16x8 v11 = *(const bf16x8*)&Vl[(q + 32) * 64 + ((2 | hi) ^ (q & 7)) * 8];
            bf16x8 v12 = *(const bf16x8*)&Vl[(q + 32) * 64 + ((4 | hi) ^ (q & 7)) * 8];
            bf16x8 v13 = *(const bf16x8*)&Vl[(q + 32) * 64 + ((6 | hi) ^ (q & 7)) * 8];
            __builtin_amdgcn_s_setprio(1);
            oacc0 = __builtin_amdgcn_mfma_f32_32x32x16_bf16(v00, pf0.v, oacc0, 0, 0, 0);
            oacc1 = __builtin_amdgcn_mfma_f32_32x32x16_bf16(v10, pf0.v, oacc1, 0, 0, 0);
            oacc0 = __builtin_amdgcn_mfma_f32_32x32x16_bf16(v01, pf1.v, oacc0, 0, 0, 0);
            oacc1 = __builtin_amdgcn_mfma_f32_32x32x16_bf16(v11, pf1.v, oacc1, 0, 0, 0);
            oacc0 = __builtin_amdgcn_mfma_f32_32x32x16_bf16(v02, pf2.v, oacc0, 0, 0, 0);
            oacc1 = __builtin_amdgcn_mfma_f32_32x32x16_bf16(v12, pf2.v, oacc1, 0, 0, 0);
            oacc0 = __builtin_amdgcn_mfma_f32_32x32x16_bf16(v03, pf3.v, oacc0, 0, 0, 0);
            oacc1 = __builtin_amdgcn_mfma_f32_32x32x16_bf16(v13, pf3.v, oacc1, 0, 0, 0);
            __builtin_amdgcn_s_setprio(0);
        }

        __syncthreads();
    }

    const float lfull = l_ + __shfl_xor(l_, 32);
    const float invl = 1.f / lfull;
    const int wbase = w * 2048;
#pragma unroll
    for (int r = 0; r < 16; r++) {
        const int dk0 = (r & 3) + 8 * (r >> 2) + 4 * hi;
        const int dk1 = 32 + dk0;
        smem[wbase + q * 64 + (((dk0 >> 3) ^ (q & 7)) << 3) + (dk0 & 7)] = bfbits(oacc0[r] * invl);
        smem[wbase + q * 64 + (((dk1 >> 3) ^ (q & 7)) << 3) + (dk1 & 7)] = bfbits(oacc1[r] * invl);
    }
    __syncthreads();
    const int b = bh >> 4, h = bh & 15;
    const int r4 = lane >> 1;
    const int cc = (lane & 1) * 4;
#pragma unroll
    for (int c = 0; c < 4; c++) {
        const int chunk = cc + c;
        uint4 val = *(const uint4*)&smem[wbase + r4 * 64 + ((chunk ^ (r4 & 7)) << 3)];
        *(uint4*)&ctx[((size_t)(b * SEQ + q0 + r4)) * DMODEL + h * DK + chunk * 8] = val;
    }
}

// ---------------- in-place LayerNorm ----------------
__global__ __launch_bounds__(256) void ln_inplace(float* __restrict__ y,
                                                  const float* __restrict__ gamma,
                                                  const float* __restrict__ beta) {
    const int row = blockIdx.x;
    float* p = y + (size_t)row * DMODEL;
    const int tid = threadIdx.x;
    float4 v = *(const float4*)(p + tid * 4);
    float s  = v.x + v.y + v.z + v.w;
    float sq = v.x * v.x + v.y * v.y + v.z * v.z + v.w * v.w;
#pragma unroll
    for (int m = 1; m < 64; m <<= 1) {
        s  += __shfl_xor(s, m);
        sq += __shfl_xor(sq, m);
    }
    __shared__ float rs[4], rq[4];
    if ((tid & 63) == 0) { rs[tid >> 6] = s; rq[tid >> 6] = sq; }
    __syncthreads();
    s  = rs[0] + rs[1] + rs[2] + rs[3];
    sq = rq[0] + rq[1] + rq[2] + rq[3];
    const float mean = s * (1.0f / 1024.0f);
    const float var  = sq * (1.0f / 1024.0f) - mean * mean;
    const float inv  = rsqrtf(var + 1e-5f);
    const int c = tid * 4;
    float4 g4 = *(const float4*)(gamma + c);
    float4 b4 = *(const float4*)(beta + c);
    float4 o;
    o.x = (v.x - mean) * inv * g4.x + b4.x;
    o.y = (v.y - mean) * inv * g4.y + b4.y;
    o.z = (v.z - mean) * inv * g4.z + b4.z;
    o.w = (v.w - mean) * inv * g4.w + b4.w;
    *(float4*)(p + c) = o;
}

extern "C" void kernel_launch(void* const* d_in, const int* in_sizes, int n_in,
                              void* d_out, int out_size, void* d_ws, size_t ws_size,
                              hipStream_t stream) {
    const float* x     = (const float*)d_in[0];
    const float* Wq    = (const float*)d_in[1];
    const float* bq    = (const float*)d_in[2];
    const float* Wk    = (const float*)d_in[3];
    const float* bk    = (const float*)d_in[4];
    const float* Wv    = (const float*)d_in[5];
    const float* bv    = (const float*)d_in[6];
    const float* Wo    = (const float*)d_in[7];
    const float* bo    = (const float*)d_in[8];
    const float* gamma = (const float*)d_in[9];
    const float* beta  = (const float*)d_in[10];
    float* out = (float*)d_out;

    u16* x_bf    = (u16*)d_ws;
    u16* Wqkv_bf = x_bf + (size_t)NROWS * DMODEL;
    u16* Wo_bf   = Wqkv_bf + (size_t)3072 * 1024;
    u16* Q_bf    = Wo_bf + (size_t)1024 * 1024;
    u16* K_bf    = Q_bf + (size_t)64 * SEQ * DK;
    u16* Vt_bf   = K_bf + (size_t)64 * SEQ * DK;
    u16* ctx_bf  = x_bf;  // alias: x_bf dead after QKV GEMM

    cvt_all<<<12288, 256, 0, stream>>>(x, Wq, Wk, Wv, Wo,
                                       x_bf, Wqkv_bf, Wqkv_bf + 1048576,
                                       Wqkv_bf + 2097152, Wo_bf);

    gemm_qkv<<<dim3(64, 12), 512, 0, stream>>>(x_bf, Wqkv_bf,
                                               bq, bk, bv, Q_bf, K_bf, Vt_bf);
    attn<<<dim3(64, 8), 512, 0, stream>>>(Q_bf, K_bf, Vt_bf, ctx_bf);
    gemm_o<<<dim3(64, 8), 256, 0, stream>>>(ctx_bf, Wo_bf, bo, x, out);
    ln_inplace<<<8192, 256, 0, stream>>>(out, gamma, beta);
}

// Round 13
// 194.107 us; speedup vs baseline: 1.1179x; 1.0308x over previous
//
#include <hip/hip_runtime.h>

// Fused MHA block: out = LayerNorm(x + MHA(x)).  B=4, S=2048, D=1024, H=16, dk=64.
// bf16 MFMA internal, fp32 I/O.
//
// Round 13: unified counted-vmcnt GEMM template at 2 blocks/CU.
//  R12 post-mortem: 128x256 + 96KB LDS = 1 block/CU -> nothing to overlap the
//  vmcnt+barrier drain. New gemm_piped<EPI>: 128x128, BK=64, 512thr = 8 waves
//  (4x2, 32x64/wave, 32 acc f32 -> ~80 regs), LDS 64KB (2 dbuf) -> 2 blocks/CU
//  co-resident; per-wave 4 loads/tile -> s_waitcnt vmcnt(4) in-loop (never 0),
//  raw s_barrier. Counted-wait (T4) + inter-block overlap (m97 mechanism).
//  EPI 0 = QKV (Q/K direct, V LDS-transpose bounce), EPI 1 = O-proj+res.
//  attn = R9 body (93.8us). cvt_all, ln unchanged.

#define SEQ 2048
#define DMODEL 1024
#define NH 16
#define DK 64
#define NROWS 8192  // B*S

typedef unsigned short u16;
typedef unsigned int u32;
typedef __bf16 bf16;
typedef bf16 bf16x8 __attribute__((ext_vector_type(8)));
typedef float f32x4 __attribute__((ext_vector_type(4)));
typedef float f32x16 __attribute__((ext_vector_type(16)));
typedef unsigned u32x2 __attribute__((ext_vector_type(2)));

__device__ inline u16 bfbits(float f) { return __builtin_bit_cast(u16, (bf16)f); }
__device__ inline u32 packbf2(float a, float b) {
    return (u32)bfbits(a) | ((u32)bfbits(b) << 16);
}

// Schraudolph exp2 (validated R8+): full-rate VALU, error cancels in norm.
__device__ inline float sexp2(float s) {
    return __builtin_bit_cast(float, (u32)(int)fmaf(s, 8388608.0f, 1064986823.0f));
}

// async global->LDS, 16B per lane; LDS dest = wave-uniform base + lane*16
__device__ inline void gload16(const u16* g, u16* l) {
    __builtin_amdgcn_global_load_lds(
        (const __attribute__((address_space(1))) u32*)g,
        (__attribute__((address_space(3))) u32*)l, 16, 0, 0);
}

// cross-half exchange (validated rounds 2-12)
__device__ inline void plswap(u32& a, u32& b) {
#if __has_builtin(__builtin_amdgcn_permlane32_swap)
    u32x2 r = __builtin_amdgcn_permlane32_swap(a, b, false, false);
    a = r[0]; b = r[1];
#else
    u32 xa = __shfl_xor(a, 32), xb = __shfl_xor(b, 32);
    int hi = (threadIdx.x & 63) >> 5;
    u32 na = hi ? xb : a;
    u32 nb = hi ? b : xa;
    a = na; b = nb;
#endif
}

// ---------------- fused fp32 -> bf16 convert: x + 4 weights ----------------
__global__ __launch_bounds__(256) void cvt_all(
    const float* __restrict__ x,  const float* __restrict__ w0,
    const float* __restrict__ w1, const float* __restrict__ w2,
    const float* __restrict__ w3,
    u16* __restrict__ xo, u16* __restrict__ o0, u16* __restrict__ o1,
    u16* __restrict__ o2, u16* __restrict__ o3) {
    const int b = blockIdx.x;
    const float* in;
    u16* out;
    int base;
    if (b < 8192) {
        in = x; out = xo; base = b << 10;
    } else {
        const int wsel = (b - 8192) >> 10;
        base = ((b - 8192) & 1023) << 10;
        switch (wsel) {
            case 0: in = w0; out = o0; break;
            case 1: in = w1; out = o1; break;
            case 2: in = w2; out = o2; break;
            default: in = w3; out = o3; break;
        }
    }
    const int i = base + threadIdx.x * 4;
    float4 v = *(const float4*)(in + i);
    ushort4 o;
    o.x = bfbits(v.x); o.y = bfbits(v.y); o.z = bfbits(v.z); o.w = bfbits(v.w);
    *(ushort4*)(out + i) = o;
}

// ---------------- unified counted-vmcnt GEMM: C = A[.,1024] @ W[.,1024]^T ----------------
// BM=BN=128, BK=64, 512 thr = 8 waves (4 row-groups x 2 col-groups; wave tile
// 32x64 = 2x4 frags). LDS 64KB: As[2] 2x8192 elems @0, Bs[2] @16384.
// Per wave per K-tile: 2 A-issues + 2 B-issues = 4 gload16 -> vmcnt(4) in-loop.
// EPI 0: QKV quadrant epilogue (n0>>10: 0=Q,1=K,2=V-bounce). EPI 1: O+residual.
template <int EPI>
__global__ __launch_bounds__(512) void gemm_piped(
    const u16* __restrict__ A, const u16* __restrict__ Bm,
    const float* __restrict__ bias0, const float* __restrict__ bias1,
    const float* __restrict__ bias2,
    u16* __restrict__ Qo, u16* __restrict__ Ko, u16* __restrict__ Vo,
    const float* __restrict__ xres, float* __restrict__ yout) {
    __shared__ __align__(16) u16 smem[32768];   // As[2]@0, Bs[2]@16384 (elems)

    const int tid  = threadIdx.x;
    const int lane = tid & 63;
    const int w    = tid >> 6;       // 0..7
    const int wr   = (w >> 1) * 32;  // row base: 4 groups of 32
    const int wc   = (w & 1) * 64;   // col base: 2 groups of 64
    const int l16  = lane & 15;
    const int lq   = lane >> 4;
    const int m0   = blockIdx.x * 128;
    const int n0   = blockIdx.y * 128;

    f32x4 acc[2][4];
#pragma unroll
    for (int m = 0; m < 2; m++)
#pragma unroll
        for (int n = 0; n < 4; n++) {
            f32x4 z = {0.f, 0.f, 0.f, 0.f};
            acc[m][n] = z;
        }

    // staging: wave w stages A rows {w*8..w*8+8, 64+w*8..} and same for B.
    // lane: row-in-8 = l>>3, pre-swizzled source chunk = (l&7)^(l>>3).
    const int l8r = lane >> 3;
    const int sch = (lane & 7) ^ l8r;
    const u16* a_g = A  + (size_t)(m0 + w * 8 + l8r) * 1024 + sch * 8;
    const u16* b_g = Bm + (size_t)(n0 + w * 8 + l8r) * 1024 + sch * 8;
    u16* asd = smem + w * 512;           // +4096 for rows 64+, +c*8192 per buffer
    u16* bsd = smem + 16384 + w * 512;

#define STAGE(kt, c) do {                                              \
        gload16(a_g + (kt) * 64,         asd + (c) * 8192);            \
        gload16(a_g + 65536 + (kt) * 64, asd + (c) * 8192 + 4096);     \
        gload16(b_g + (kt) * 64,         bsd + (c) * 8192);            \
        gload16(b_g + 65536 + (kt) * 64, bsd + (c) * 8192 + 4096);     \
    } while (0)

    STAGE(0, 0);
    STAGE(1, 1);

    for (int kt = 0; kt < 16; kt++) {
        const int cur = kt & 1;
        // counted wait: outstanding = T_kt remnants + T_{kt+1}(4 newest);
        // vmcnt(4) => T_kt fully landed, T_{kt+1} stays in flight.
        if (kt < 15) asm volatile("s_waitcnt vmcnt(4)" ::: "memory");
        else         asm volatile("s_waitcnt vmcnt(0)" ::: "memory");
        __builtin_amdgcn_s_barrier();

        const u16* Asl = smem + cur * 8192;
        const u16* Bsl = smem + 16384 + cur * 8192;
#pragma unroll
        for (int kk = 0; kk < 2; kk++) {
            bf16x8 af[2], bfr[4];
#pragma unroll
            for (int m = 0; m < 2; m++)
                af[m] = *(const bf16x8*)&Asl[(wr + m * 16 + l16) * 64 +
                                             (((kk << 2) | lq) ^ (l16 & 7)) * 8];
#pragma unroll
            for (int n = 0; n < 4; n++)
                bfr[n] = *(const bf16x8*)&Bsl[(wc + n * 16 + l16) * 64 +
                                              (((kk << 2) | lq) ^ (l16 & 7)) * 8];
            __builtin_amdgcn_s_setprio(1);
#pragma unroll
            for (int m = 0; m < 2; m++)
#pragma unroll
                for (int n = 0; n < 4; n++)
                    acc[m][n] = __builtin_amdgcn_mfma_f32_16x16x32_bf16(
                        af[m], bfr[n], acc[m][n], 0, 0, 0);
            __builtin_amdgcn_s_setprio(0);
        }
        __builtin_amdgcn_s_barrier();    // all waves done reading buf[cur]
        if (kt < 14) STAGE(kt + 2, cur); // overwrite buf[cur] with tile kt+2
    }
#undef STAGE

    if (EPI == 0 && n0 >= 2048) {
        // ---- V quadrant: LDS-transpose bounce -> coalesced V^T stores ----
        const int e0 = n0 - 2048;
#pragma unroll
        for (int m = 0; m < 2; m++)
#pragma unroll
            for (int n = 0; n < 4; n++) {
                const int col = wc + n * 16 + l16;       // local e, 0..127
                const int row = wr + lq * 4 + m * 16;    // local s, 4-aligned
                const float bias = bias2[e0 + col];
                ushort4 pk;
                pk.x = bfbits(acc[m][n][0] + bias);
                pk.y = bfbits(acc[m][n][1] + bias);
                pk.z = bfbits(acc[m][n][2] + bias);
                pk.w = bfbits(acc[m][n][3] + bias);
                *(ushort4*)&smem[col * 128 + (row ^ ((col & 7) << 3))] = pk;
            }
        __syncthreads();
        const int b = m0 >> 11;
        const int sbase = m0 & 2047;
#pragma unroll
        for (int i = 0; i < 4; i++) {
            const int c = tid + 512 * i;     // 0..2047
            const int col = c >> 4;          // 0..127
            const int s0 = (c & 15) * 8;     // 0..120
            uint4 val = *(const uint4*)&smem[col * 128 + (s0 ^ ((col & 7) << 3))];
            const int eg = e0 + col;
            const int bh = b * NH + (eg >> 6);
            *(uint4*)&Vo[((size_t)bh * DK + (eg & 63)) * SEQ + sbase + s0] = val;
        }
        return;
    }

    const int rbase = m0 + wr + lq * 4;
#pragma unroll
    for (int m = 0; m < 2; m++)
#pragma unroll
        for (int n = 0; n < 4; n++) {
            if (EPI == 0) {
                const int which = n0 >> 10;              // 0=Q, 1=K (block-uniform)
                const int e = (n0 & 1023) + wc + n * 16 + l16;
                const float bias = (which == 0) ? bias0[e] : bias1[e];
                const int h = e >> 6, d = e & 63;
#pragma unroll
                for (int r = 0; r < 4; r++) {
                    const int row = rbase + m * 16 + r;
                    float v = acc[m][n][r] + bias;
                    if (which == 0) v *= 0.18033688011112042f;  // 1/sqrt(dk)*log2e
                    const int b = row >> 11, s = row & 2047;
                    const int bh = b * NH + h;
                    if (which == 0)
                        Qo[((size_t)bh * SEQ + s) * DK + d] = bfbits(v);
                    else
                        Ko[((size_t)bh * SEQ + s) * DK + d] = bfbits(v);
                }
            } else {
                const int col = n0 + wc + n * 16 + l16;
#pragma unroll
                for (int r = 0; r < 4; r++) {
                    const int row = rbase + m * 16 + r;
                    float v = acc[m][n][r] + bias0[col] + xres[(size_t)row * DMODEL + col];
                    yout[(size_t)row * DMODEL + col] = v;
                }
            }
        }
}

// ---------------- flash attention (R9 body: 93.8us) ----------------
__global__ __launch_bounds__(512) void attn(const u16* __restrict__ Qb,
                                            const u16* __restrict__ Kb,
                                            const u16* __restrict__ Vtb,
                                            u16* __restrict__ ctx) {
    __shared__ __align__(16) u16 smem[16384];

    const int tid  = threadIdx.x;
    const int lane = tid & 63;
    const int w    = tid >> 6;
    const int q    = lane & 31;
    const int hi   = lane >> 5;
    const int bh   = blockIdx.x;
    const int q0   = blockIdx.y * 256 + w * 32;

    const u16* qp = Qb + ((size_t)bh * SEQ + q0 + q) * DK + hi * 8;
    bf16x8 qf0 = *(const bf16x8*)(qp);
    bf16x8 qf1 = *(const bf16x8*)(qp + 16);
    bf16x8 qf2 = *(const bf16x8*)(qp + 32);
    bf16x8 qf3 = *(const bf16x8*)(qp + 48);

    const int l8r = lane >> 3;
    const int sch = (lane & 7) ^ l8r;
    const u16* kg = Kb  + ((size_t)bh * SEQ + w * 8 + l8r) * 64 + sch * 8;
    const u16* vg = Vtb + ((size_t)bh * DK  + w * 8 + l8r) * SEQ + sch * 8;
    u16* kl = smem + w * 512;
    u16* vl = smem + 8192 + w * 512;

    f32x16 oacc0, oacc1;
#pragma unroll
    for (int r = 0; r < 16; r++) { oacc0[r] = 0.f; oacc1[r] = 0.f; }
    f32x16 fzero;
#pragma unroll
    for (int r = 0; r < 16; r++) fzero[r] = 0.f;
    float l_ = 0.f;

    gload16(kg, kl);
    gload16(vg, vl);
    __syncthreads();

    for (int t = 0; t < SEQ / 64; t++) {
        if (t < SEQ / 64 - 1) {
            gload16(kg + (size_t)(t + 1) * 4096, kl + ((t + 1) & 1) * 4096);
            gload16(vg + (size_t)(t + 1) * 64,  vl + ((t + 1) & 1) * 4096);
        }
        const u16* Kl = smem + (t & 1) * 4096;
        const u16* Vl = smem + 8192 + (t & 1) * 4096;

        f32x16 sacc0, sacc1;
        {
            bf16x8 k00 = *(const bf16x8*)&Kl[(q)      * 64 + ((0 | hi) ^ (q & 7)) * 8];
            bf16x8 k01 = *(const bf16x8*)&Kl[(q)      * 64 + ((2 | hi) ^ (q & 7)) * 8];
            bf16x8 k02 = *(const bf16x8*)&Kl[(q)      * 64 + ((4 | hi) ^ (q & 7)) * 8];
            bf16x8 k03 = *(const bf16x8*)&Kl[(q)      * 64 + ((6 | hi) ^ (q & 7)) * 8];
            bf16x8 k10 = *(const bf16x8*)&Kl[(q + 32) * 64 + ((0 | hi) ^ (q & 7)) * 8];
            bf16x8 k11 = *(const bf16x8*)&Kl[(q + 32) * 64 + ((2 | hi) ^ (q & 7)) * 8];
            bf16x8 k12 = *(const bf16x8*)&Kl[(q + 32) * 64 + ((4 | hi) ^ (q & 7)) * 8];
            bf16x8 k13 = *(const bf16x8*)&Kl[(q + 32) * 64 + ((6 | hi) ^ (q & 7)) * 8];
            __builtin_amdgcn_s_setprio(1);
            sacc0 = __builtin_amdgcn_mfma_f32_32x32x16_bf16(k00, qf0, fzero, 0, 0, 0);
            sacc1 = __builtin_amdgcn_mfma_f32_32x32x16_bf16(k10, qf0, fzero, 0, 0, 0);
            sacc0 = __builtin_amdgcn_mfma_f32_32x32x16_bf16(k01, qf1, sacc0, 0, 0, 0);
            sacc1 = __builtin_amdgcn_mfma_f32_32x32x16_bf16(k11, qf1, sacc1, 0, 0, 0);
            sacc0 = __builtin_amdgcn_mfma_f32_32x32x16_bf16(k02, qf2, sacc0, 0, 0, 0);
            sacc1 = __builtin_amdgcn_mfma_f32_32x32x16_bf16(k12, qf2, sacc1, 0, 0, 0);
            sacc0 = __builtin_amdgcn_mfma_f32_32x32x16_bf16(k03, qf3, sacc0, 0, 0, 0);
            sacc1 = __builtin_amdgcn_mfma_f32_32x32x16_bf16(k13, qf3, sacc1, 0, 0, 0);
            __builtin_amdgcn_s_setprio(0);
        }

#pragma unroll
        for (int r = 0; r < 16; r++) sacc0[r] = sexp2(sacc0[r]);
#pragma unroll
        for (int r = 0; r < 16; r++) sacc1[r] = sexp2(sacc1[r]);
        {
            float s0 = ((sacc0[0] + sacc0[1]) + (sacc0[2] + sacc0[3])) +
                       ((sacc0[4] + sacc0[5]) + (sacc0[6] + sacc0[7]));
            float s1 = ((sacc0[8] + sacc0[9]) + (sacc0[10] + sacc0[11])) +
                       ((sacc0[12] + sacc0[13]) + (sacc0[14] + sacc0[15]));
            float s2 = ((sacc1[0] + sacc1[1]) + (sacc1[2] + sacc1[3])) +
                       ((sacc1[4] + sacc1[5]) + (sacc1[6] + sacc1[7]));
            float s3 = ((sacc1[8] + sacc1[9]) + (sacc1[10] + sacc1[11])) +
                       ((sacc1[12] + sacc1[13]) + (sacc1[14] + sacc1[15]));
            l_ += (s0 + s1) + (s2 + s3);
        }

        u32 wa[8], wb[8];
#pragma unroll
        for (int i = 0; i < 8; i++) wa[i] = packbf2(sacc0[2 * i], sacc0[2 * i + 1]);
#pragma unroll
        for (int i = 0; i < 8; i++) wb[i] = packbf2(sacc1[2 * i], sacc1[2 * i + 1]);
        plswap(wa[0], wa[2]); plswap(wa[1], wa[3]);
        plswap(wa[4], wa[6]); plswap(wa[5], wa[7]);
        plswap(wb[0], wb[2]); plswap(wb[1], wb[3]);
        plswap(wb[4], wb[6]); plswap(wb[5], wb[7]);
        union { u32 u[4]; bf16x8 v; } pf0, pf1, pf2, pf3;
        pf0.u[0] = wa[0]; pf0.u[1] = wa[1]; pf0.u[2] = wa[2]; pf0.u[3] = wa[3];
        pf1.u[0] = wa[4]; pf1.u[1] = wa[5]; pf1.u[2] = wa[6]; pf1.u[3] = wa[7];
        pf2.u[0] = wb[0]; pf2.u[1] = wb[1]; pf2.u[2] = wb[2]; pf2.u[3] = wb[3];
        pf3.u[0] = wb[4]; pf3.u[1] = wb[5]; pf3.u[2] = wb[6]; pf3.u[3] = wb[7];

        {
            bf16x8 v00 = *(const bf16x8*)&Vl[(q)      * 64 + ((0 | hi) ^ (q & 7)) * 8];
            bf16x8 v01 = *(const bf16x8*)&Vl[(q)      * 64 + ((2 | hi) ^ (q & 7)) * 8];
            bf16x8 v02 = *(const bf16x8*)&Vl[(q)      * 64 + ((4 | hi) ^ (q & 7)) * 8];
            bf16x8 v03 = *(const bf16x8*)&Vl[(q)      * 64 + ((6 | hi) ^ (q & 7)) * 8];
            bf16x8 v10 = *(const bf16x8*)&Vl[(q + 32) * 64 + ((0 | hi) ^ (q & 7)) * 8];
            bf16x8 v11 = *(const bf16x8*)&Vl[(q + 32) * 64 + ((2 | hi) ^ (q & 7)) * 8];
            bf16x8 v12 = *(const bf16x8*)&Vl[(q + 32) * 64 + ((4 | hi) ^ (q & 7)) * 8];
            bf16x8 v13 = *(const bf16x8*)&Vl[(q + 32) * 64 + ((6 | hi) ^ (q & 7)) * 8];
            __builtin_amdgcn_s_setprio(1);
            oacc0 = __builtin_amdgcn_mfma_f32_32x32x16_bf16(v00, pf0.v, oacc0, 0, 0, 0);
            oacc1 = __builtin_amdgcn_mfma_f32_32x32x16_bf16(v10, pf0.v, oacc1, 0, 0, 0);
            oacc0 = __builtin_amdgcn_mfma_f32_32x32x16_bf16(v01, pf1.v, oacc0, 0, 0, 0);
            oacc1 = __builtin_amdgcn_mfma_f32_32x32x16_bf16(v11, pf1.v, oacc1, 0, 0, 0);
            oacc0 = __builtin_amdgcn_mfma_f32_32x32x16_bf16(v02, pf2.v, oacc0, 0, 0, 0);
            oacc1 = __builtin_amdgcn_mfma_f32_32x32x16_bf16(v12, pf2.v, oacc1, 0, 0, 0);
            oacc0 = __builtin_amdgcn_mfma_f32_32x32x16_bf16(v03, pf3.v, oacc0, 0, 0, 0);
            oacc1 = __builtin_amdgcn_mfma_f32_32x32x16_bf16(v13, pf3.v, oacc1, 0, 0, 0);
            __builtin_amdgcn_s_setprio(0);
        }

        __syncthreads();
    }

    const float lfull = l_ + __shfl_xor(l_, 32);
    const float invl = 1.f / lfull;
    const int wbase = w * 2048;
#pragma unroll
    for (int r = 0; r < 16; r++) {
        const int dk0 = (r & 3) + 8 * (r >> 2) + 4 * hi;
        const int dk1 = 32 + dk0;
        smem[wbase + q * 64 + (((dk0 >> 3) ^ (q & 7)) << 3) + (dk0 & 7)] = bfbits(oacc0[r] * invl);
        smem[wbase + q * 64 + (((dk1 >> 3) ^ (q & 7)) << 3) + (dk1 & 7)] = bfbits(oacc1[r] * invl);
    }
    __syncthreads();
    const int b = bh >> 4, h = bh & 15;
    const int r4 = lane >> 1;
    const int cc = (lane & 1) * 4;
#pragma unroll
    for (int c = 0; c < 4; c++) {
        const int chunk = cc + c;
        uint4 val = *(const uint4*)&smem[wbase + r4 * 64 + ((chunk ^ (r4 & 7)) << 3)];
        *(uint4*)&ctx[((size_t)(b * SEQ + q0 + r4)) * DMODEL + h * DK + chunk * 8] = val;
    }
}

// ---------------- in-place LayerNorm ----------------
__global__ __launch_bounds__(256) void ln_inplace(float* __restrict__ y,
                                                  const float* __restrict__ gamma,
                                                  const float* __restrict__ beta) {
    const int row = blockIdx.x;
    float* p = y + (size_t)row * DMODEL;
    const int tid = threadIdx.x;
    float4 v = *(const float4*)(p + tid * 4);
    float s  = v.x + v.y + v.z + v.w;
    float sq = v.x * v.x + v.y * v.y + v.z * v.z + v.w * v.w;
#pragma unroll
    for (int m = 1; m < 64; m <<= 1) {
        s  += __shfl_xor(s, m);
        sq += __shfl_xor(sq, m);
    }
    __shared__ float rs[4], rq[4];
    if ((tid & 63) == 0) { rs[tid >> 6] = s; rq[tid >> 6] = sq; }
    __syncthreads();
    s  = rs[0] + rs[1] + rs[2] + rs[3];
    sq = rq[0] + rq[1] + rq[2] + rq[3];
    const float mean = s * (1.0f / 1024.0f);
    const float var  = sq * (1.0f / 1024.0f) - mean * mean;
    const float inv  = rsqrtf(var + 1e-5f);
    const int c = tid * 4;
    float4 g4 = *(const float4*)(gamma + c);
    float4 b4 = *(const float4*)(beta + c);
    float4 o;
    o.x = (v.x - mean) * inv * g4.x + b4.x;
    o.y = (v.y - mean) * inv * g4.y + b4.y;
    o.z = (v.z - mean) * inv * g4.z + b4.z;
    o.w = (v.w - mean) * inv * g4.w + b4.w;
    *(float4*)(p + c) = o;
}

extern "C" void kernel_launch(void* const* d_in, const int* in_sizes, int n_in,
                              void* d_out, int out_size, void* d_ws, size_t ws_size,
                              hipStream_t stream) {
    const float* x     = (const float*)d_in[0];
    const float* Wq    = (const float*)d_in[1];
    const float* bq    = (const float*)d_in[2];
    const float* Wk    = (const float*)d_in[3];
    const float* bk    = (const float*)d_in[4];
    const float* Wv    = (const float*)d_in[5];
    const float* bv    = (const float*)d_in[6];
    const float* Wo    = (const float*)d_in[7];
    const float* bo    = (const float*)d_in[8];
    const float* gamma = (const float*)d_in[9];
    const float* beta  = (const float*)d_in[10];
    float* out = (float*)d_out;

    u16* x_bf    = (u16*)d_ws;
    u16* Wqkv_bf = x_bf + (size_t)NROWS * DMODEL;
    u16* Wo_bf   = Wqkv_bf + (size_t)3072 * 1024;
    u16* Q_bf    = Wo_bf + (size_t)1024 * 1024;
    u16* K_bf    = Q_bf + (size_t)64 * SEQ * DK;
    u16* Vt_bf   = K_bf + (size_t)64 * SEQ * DK;
    u16* ctx_bf  = x_bf;  // alias: x_bf dead after QKV GEMM

    cvt_all<<<12288, 256, 0, stream>>>(x, Wq, Wk, Wv, Wo,
                                       x_bf, Wqkv_bf, Wqkv_bf + 1048576,
                                       Wqkv_bf + 2097152, Wo_bf);

    gemm_piped<0><<<dim3(64, 24), 512, 0, stream>>>(x_bf, Wqkv_bf,
                                                    bq, bk, bv, Q_bf, K_bf, Vt_bf,
                                                    nullptr, nullptr);
    attn<<<dim3(64, 8), 512, 0, stream>>>(Q_bf, K_bf, Vt_bf, ctx_bf);
    gemm_piped<1><<<dim3(64, 8), 512, 0, stream>>>(ctx_bf, Wo_bf,
                                                   bo, nullptr, nullptr,
                                                   nullptr, nullptr, nullptr,
                                                   x, out);
    ln_inplace<<<8192, 256, 0, stream>>>(out, gamma, beta);
}

// Round 14
// 185.833 us; speedup vs baseline: 1.1677x; 1.0445x over previous
//
#include <hip/hip_runtime.h>

// Fused MHA block: out = LayerNorm(x + MHA(x)).  B=4, S=2048, D=1024, H=16, dk=64.
// bf16 MFMA internal, fp32 I/O.
//
// Round 14 = Round 13 (194.1us) + attn l-sum via packed v_dot2_f32_bf16:
//  the 30-add f32 sum tree becomes 16 dot2 ops on the ALREADY-PACKED bf16 P
//  words (la/lb partials, 8-deep chains, merged once at end). l now sums the
//  same bf16-rounded p that PV consumes. __has_builtin-guarded with the old
//  tree as fallback. GEMMs (counted-vmcnt 128x128 2blk/CU), cvt, LN unchanged.

#define SEQ 2048
#define DMODEL 1024
#define NH 16
#define DK 64
#define NROWS 8192  // B*S

typedef unsigned short u16;
typedef unsigned int u32;
typedef __bf16 bf16;
typedef bf16 bf16x2 __attribute__((ext_vector_type(2)));
typedef bf16 bf16x8 __attribute__((ext_vector_type(8)));
typedef float f32x4 __attribute__((ext_vector_type(4)));
typedef float f32x16 __attribute__((ext_vector_type(16)));
typedef unsigned u32x2 __attribute__((ext_vector_type(2)));

__device__ inline u16 bfbits(float f) { return __builtin_bit_cast(u16, (bf16)f); }
__device__ inline u32 packbf2(float a, float b) {
    return (u32)bfbits(a) | ((u32)bfbits(b) << 16);
}

// Schraudolph exp2 (validated R8+): full-rate VALU, error cancels in norm.
__device__ inline float sexp2(float s) {
    return __builtin_bit_cast(float, (u32)(int)fmaf(s, 8388608.0f, 1064986823.0f));
}

// async global->LDS, 16B per lane; LDS dest = wave-uniform base + lane*16
__device__ inline void gload16(const u16* g, u16* l) {
    __builtin_amdgcn_global_load_lds(
        (const __attribute__((address_space(1))) u32*)g,
        (__attribute__((address_space(3))) u32*)l, 16, 0, 0);
}

// cross-half exchange (validated rounds 2-13)
__device__ inline void plswap(u32& a, u32& b) {
#if __has_builtin(__builtin_amdgcn_permlane32_swap)
    u32x2 r = __builtin_amdgcn_permlane32_swap(a, b, false, false);
    a = r[0]; b = r[1];
#else
    u32 xa = __shfl_xor(a, 32), xb = __shfl_xor(b, 32);
    int hi = (threadIdx.x & 63) >> 5;
    u32 na = hi ? xb : a;
    u32 nb = hi ? b : xa;
    a = na; b = nb;
#endif
}

// ---------------- fused fp32 -> bf16 convert: x + 4 weights ----------------
__global__ __launch_bounds__(256) void cvt_all(
    const float* __restrict__ x,  const float* __restrict__ w0,
    const float* __restrict__ w1, const float* __restrict__ w2,
    const float* __restrict__ w3,
    u16* __restrict__ xo, u16* __restrict__ o0, u16* __restrict__ o1,
    u16* __restrict__ o2, u16* __restrict__ o3) {
    const int b = blockIdx.x;
    const float* in;
    u16* out;
    int base;
    if (b < 8192) {
        in = x; out = xo; base = b << 10;
    } else {
        const int wsel = (b - 8192) >> 10;
        base = ((b - 8192) & 1023) << 10;
        switch (wsel) {
            case 0: in = w0; out = o0; break;
            case 1: in = w1; out = o1; break;
            case 2: in = w2; out = o2; break;
            default: in = w3; out = o3; break;
        }
    }
    const int i = base + threadIdx.x * 4;
    float4 v = *(const float4*)(in + i);
    ushort4 o;
    o.x = bfbits(v.x); o.y = bfbits(v.y); o.z = bfbits(v.z); o.w = bfbits(v.w);
    *(ushort4*)(out + i) = o;
}

// ---------------- unified counted-vmcnt GEMM (R13, unchanged) ----------------
template <int EPI>
__global__ __launch_bounds__(512) void gemm_piped(
    const u16* __restrict__ A, const u16* __restrict__ Bm,
    const float* __restrict__ bias0, const float* __restrict__ bias1,
    const float* __restrict__ bias2,
    u16* __restrict__ Qo, u16* __restrict__ Ko, u16* __restrict__ Vo,
    const float* __restrict__ xres, float* __restrict__ yout) {
    __shared__ __align__(16) u16 smem[32768];   // As[2]@0, Bs[2]@16384 (elems)

    const int tid  = threadIdx.x;
    const int lane = tid & 63;
    const int w    = tid >> 6;
    const int wr   = (w >> 1) * 32;
    const int wc   = (w & 1) * 64;
    const int l16  = lane & 15;
    const int lq   = lane >> 4;
    const int m0   = blockIdx.x * 128;
    const int n0   = blockIdx.y * 128;

    f32x4 acc[2][4];
#pragma unroll
    for (int m = 0; m < 2; m++)
#pragma unroll
        for (int n = 0; n < 4; n++) {
            f32x4 z = {0.f, 0.f, 0.f, 0.f};
            acc[m][n] = z;
        }

    const int l8r = lane >> 3;
    const int sch = (lane & 7) ^ l8r;
    const u16* a_g = A  + (size_t)(m0 + w * 8 + l8r) * 1024 + sch * 8;
    const u16* b_g = Bm + (size_t)(n0 + w * 8 + l8r) * 1024 + sch * 8;
    u16* asd = smem + w * 512;
    u16* bsd = smem + 16384 + w * 512;

#define STAGE(kt, c) do {                                              \
        gload16(a_g + (kt) * 64,         asd + (c) * 8192);            \
        gload16(a_g + 65536 + (kt) * 64, asd + (c) * 8192 + 4096);     \
        gload16(b_g + (kt) * 64,         bsd + (c) * 8192);            \
        gload16(b_g + 65536 + (kt) * 64, bsd + (c) * 8192 + 4096);     \
    } while (0)

    STAGE(0, 0);
    STAGE(1, 1);

    for (int kt = 0; kt < 16; kt++) {
        const int cur = kt & 1;
        if (kt < 15) asm volatile("s_waitcnt vmcnt(4)" ::: "memory");
        else         asm volatile("s_waitcnt vmcnt(0)" ::: "memory");
        __builtin_amdgcn_s_barrier();

        const u16* Asl = smem + cur * 8192;
        const u16* Bsl = smem + 16384 + cur * 8192;
#pragma unroll
        for (int kk = 0; kk < 2; kk++) {
            bf16x8 af[2], bfr[4];
#pragma unroll
            for (int m = 0; m < 2; m++)
                af[m] = *(const bf16x8*)&Asl[(wr + m * 16 + l16) * 64 +
                                             (((kk << 2) | lq) ^ (l16 & 7)) * 8];
#pragma unroll
            for (int n = 0; n < 4; n++)
                bfr[n] = *(const bf16x8*)&Bsl[(wc + n * 16 + l16) * 64 +
                                              (((kk << 2) | lq) ^ (l16 & 7)) * 8];
            __builtin_amdgcn_s_setprio(1);
#pragma unroll
            for (int m = 0; m < 2; m++)
#pragma unroll
                for (int n = 0; n < 4; n++)
                    acc[m][n] = __builtin_amdgcn_mfma_f32_16x16x32_bf16(
                        af[m], bfr[n], acc[m][n], 0, 0, 0);
            __builtin_amdgcn_s_setprio(0);
        }
        __builtin_amdgcn_s_barrier();
        if (kt < 14) STAGE(kt + 2, cur);
    }
#undef STAGE

    if (EPI == 0 && n0 >= 2048) {
        const int e0 = n0 - 2048;
#pragma unroll
        for (int m = 0; m < 2; m++)
#pragma unroll
            for (int n = 0; n < 4; n++) {
                const int col = wc + n * 16 + l16;
                const int row = wr + lq * 4 + m * 16;
                const float bias = bias2[e0 + col];
                ushort4 pk;
                pk.x = bfbits(acc[m][n][0] + bias);
                pk.y = bfbits(acc[m][n][1] + bias);
                pk.z = bfbits(acc[m][n][2] + bias);
                pk.w = bfbits(acc[m][n][3] + bias);
                *(ushort4*)&smem[col * 128 + (row ^ ((col & 7) << 3))] = pk;
            }
        __syncthreads();
        const int b = m0 >> 11;
        const int sbase = m0 & 2047;
#pragma unroll
        for (int i = 0; i < 4; i++) {
            const int c = tid + 512 * i;
            const int col = c >> 4;
            const int s0 = (c & 15) * 8;
            uint4 val = *(const uint4*)&smem[col * 128 + (s0 ^ ((col & 7) << 3))];
            const int eg = e0 + col;
            const int bh = b * NH + (eg >> 6);
            *(uint4*)&Vo[((size_t)bh * DK + (eg & 63)) * SEQ + sbase + s0] = val;
        }
        return;
    }

    const int rbase = m0 + wr + lq * 4;
#pragma unroll
    for (int m = 0; m < 2; m++)
#pragma unroll
        for (int n = 0; n < 4; n++) {
            if (EPI == 0) {
                const int which = n0 >> 10;
                const int e = (n0 & 1023) + wc + n * 16 + l16;
                const float bias = (which == 0) ? bias0[e] : bias1[e];
                const int h = e >> 6, d = e & 63;
#pragma unroll
                for (int r = 0; r < 4; r++) {
                    const int row = rbase + m * 16 + r;
                    float v = acc[m][n][r] + bias;
                    if (which == 0) v *= 0.18033688011112042f;
                    const int b = row >> 11, s = row & 2047;
                    const int bh = b * NH + h;
                    if (which == 0)
                        Qo[((size_t)bh * SEQ + s) * DK + d] = bfbits(v);
                    else
                        Ko[((size_t)bh * SEQ + s) * DK + d] = bfbits(v);
                }
            } else {
                const int col = n0 + wc + n * 16 + l16;
#pragma unroll
                for (int r = 0; r < 4; r++) {
                    const int row = rbase + m * 16 + r;
                    float v = acc[m][n][r] + bias0[col] + xres[(size_t)row * DMODEL + col];
                    yout[(size_t)row * DMODEL + col] = v;
                }
            }
        }
}

// ---------------- flash attention (R9 body + dot2 l-sum) ----------------
__global__ __launch_bounds__(512) void attn(const u16* __restrict__ Qb,
                                            const u16* __restrict__ Kb,
                                            const u16* __restrict__ Vtb,
                                            u16* __restrict__ ctx) {
    __shared__ __align__(16) u16 smem[16384];

    const int tid  = threadIdx.x;
    const int lane = tid & 63;
    const int w    = tid >> 6;
    const int q    = lane & 31;
    const int hi   = lane >> 5;
    const int bh   = blockIdx.x;
    const int q0   = blockIdx.y * 256 + w * 32;

    const u16* qp = Qb + ((size_t)bh * SEQ + q0 + q) * DK + hi * 8;
    bf16x8 qf0 = *(const bf16x8*)(qp);
    bf16x8 qf1 = *(const bf16x8*)(qp + 16);
    bf16x8 qf2 = *(const bf16x8*)(qp + 32);
    bf16x8 qf3 = *(const bf16x8*)(qp + 48);

    const int l8r = lane >> 3;
    const int sch = (lane & 7) ^ l8r;
    const u16* kg = Kb  + ((size_t)bh * SEQ + w * 8 + l8r) * 64 + sch * 8;
    const u16* vg = Vtb + ((size_t)bh * DK  + w * 8 + l8r) * SEQ + sch * 8;
    u16* kl = smem + w * 512;
    u16* vl = smem + 8192 + w * 512;

    f32x16 oacc0, oacc1;
#pragma unroll
    for (int r = 0; r < 16; r++) { oacc0[r] = 0.f; oacc1[r] = 0.f; }
    f32x16 fzero;
#pragma unroll
    for (int r = 0; r < 16; r++) fzero[r] = 0.f;
    float la = 0.f, lb = 0.f;   // packed-dot partials (or tree partials in fallback)

#if __has_builtin(__builtin_amdgcn_fdot2_f32_bf16)
    bf16x2 ones2;
    ones2[0] = (bf16)1.0f; ones2[1] = (bf16)1.0f;
#endif

    gload16(kg, kl);
    gload16(vg, vl);
    __syncthreads();

    for (int t = 0; t < SEQ / 64; t++) {
        if (t < SEQ / 64 - 1) {
            gload16(kg + (size_t)(t + 1) * 4096, kl + ((t + 1) & 1) * 4096);
            gload16(vg + (size_t)(t + 1) * 64,  vl + ((t + 1) & 1) * 4096);
        }
        const u16* Kl = smem + (t & 1) * 4096;
        const u16* Vl = smem + 8192 + (t & 1) * 4096;

        f32x16 sacc0, sacc1;
        {
            bf16x8 k00 = *(const bf16x8*)&Kl[(q)      * 64 + ((0 | hi) ^ (q & 7)) * 8];
            bf16x8 k01 = *(const bf16x8*)&Kl[(q)      * 64 + ((2 | hi) ^ (q & 7)) * 8];
            bf16x8 k02 = *(const bf16x8*)&Kl[(q)      * 64 + ((4 | hi) ^ (q & 7)) * 8];
            bf16x8 k03 = *(const bf16x8*)&Kl[(q)      * 64 + ((6 | hi) ^ (q & 7)) * 8];
            bf16x8 k10 = *(const bf16x8*)&Kl[(q + 32) * 64 + ((0 | hi) ^ (q & 7)) * 8];
            bf16x8 k11 = *(const bf16x8*)&Kl[(q + 32) * 64 + ((2 | hi) ^ (q & 7)) * 8];
            bf16x8 k12 = *(const bf16x8*)&Kl[(q + 32) * 64 + ((4 | hi) ^ (q & 7)) * 8];
            bf16x8 k13 = *(const bf16x8*)&Kl[(q + 32) * 64 + ((6 | hi) ^ (q & 7)) * 8];
            __builtin_amdgcn_s_setprio(1);
            sacc0 = __builtin_amdgcn_mfma_f32_32x32x16_bf16(k00, qf0, fzero, 0, 0, 0);
            sacc1 = __builtin_amdgcn_mfma_f32_32x32x16_bf16(k10, qf0, fzero, 0, 0, 0);
            sacc0 = __builtin_amdgcn_mfma_f32_32x32x16_bf16(k01, qf1, sacc0, 0, 0, 0);
            sacc1 = __builtin_amdgcn_mfma_f32_32x32x16_bf16(k11, qf1, sacc1, 0, 0, 0);
            sacc0 = __builtin_amdgcn_mfma_f32_32x32x16_bf16(k02, qf2, sacc0, 0, 0, 0);
            sacc1 = __builtin_amdgcn_mfma_f32_32x32x16_bf16(k12, qf2, sacc1, 0, 0, 0);
            sacc0 = __builtin_amdgcn_mfma_f32_32x32x16_bf16(k03, qf3, sacc0, 0, 0, 0);
            sacc1 = __builtin_amdgcn_mfma_f32_32x32x16_bf16(k13, qf3, sacc1, 0, 0, 0);
            __builtin_amdgcn_s_setprio(0);
        }

#pragma unroll
        for (int r = 0; r < 16; r++) sacc0[r] = sexp2(sacc0[r]);
#pragma unroll
        for (int r = 0; r < 16; r++) sacc1[r] = sexp2(sacc1[r]);

        u32 wa[8], wb[8];
#pragma unroll
        for (int i = 0; i < 8; i++) wa[i] = packbf2(sacc0[2 * i], sacc0[2 * i + 1]);
#pragma unroll
        for (int i = 0; i < 8; i++) wb[i] = packbf2(sacc1[2 * i], sacc1[2 * i + 1]);

#if __has_builtin(__builtin_amdgcn_fdot2_f32_bf16)
        // l-sum on the packed bf16 p words (the SAME values PV consumes):
        // 16 dot2 ops, two 8-deep chains.
#pragma unroll
        for (int i = 0; i < 8; i++)
            la = __builtin_amdgcn_fdot2_f32_bf16(
                __builtin_bit_cast(bf16x2, wa[i]), ones2, la, false);
#pragma unroll
        for (int i = 0; i < 8; i++)
            lb = __builtin_amdgcn_fdot2_f32_bf16(
                __builtin_bit_cast(bf16x2, wb[i]), ones2, lb, false);
#else
        {
            float s0 = ((sacc0[0] + sacc0[1]) + (sacc0[2] + sacc0[3])) +
                       ((sacc0[4] + sacc0[5]) + (sacc0[6] + sacc0[7]));
            float s1 = ((sacc0[8] + sacc0[9]) + (sacc0[10] + sacc0[11])) +
                       ((sacc0[12] + sacc0[13]) + (sacc0[14] + sacc0[15]));
            float s2 = ((sacc1[0] + sacc1[1]) + (sacc1[2] + sacc1[3])) +
                       ((sacc1[4] + sacc1[5]) + (sacc1[6] + sacc1[7]));
            float s3 = ((sacc1[8] + sacc1[9]) + (sacc1[10] + sacc1[11])) +
                       ((sacc1[12] + sacc1[13]) + (sacc1[14] + sacc1[15]));
            la += (s0 + s1);
            lb += (s2 + s3);
        }
#endif

        plswap(wa[0], wa[2]); plswap(wa[1], wa[3]);
        plswap(wa[4], wa[6]); plswap(wa[5], wa[7]);
        plswap(wb[0], wb[2]); plswap(wb[1], wb[3]);
        plswap(wb[4], wb[6]); plswap(wb[5], wb[7]);
        union { u32 u[4]; bf16x8 v; } pf0, pf1, pf2, pf3;
        pf0.u[0] = wa[0]; pf0.u[1] = wa[1]; pf0.u[2] = wa[2]; pf0.u[3] = wa[3];
        pf1.u[0] = wa[4]; pf1.u[1] = wa[5]; pf1.u[2] = wa[6]; pf1.u[3] = wa[7];
        pf2.u[0] = wb[0]; pf2.u[1] = wb[1]; pf2.u[2] = wb[2]; pf2.u[3] = wb[3];
        pf3.u[0] = wb[4]; pf3.u[1] = wb[5]; pf3.u[2] = wb[6]; pf3.u[3] = wb[7];

        {
            bf16x8 v00 = *(const bf16x8*)&Vl[(q)      * 64 + ((0 | hi) ^ (q & 7)) * 8];
            bf16x8 v01 = *(const bf16x8*)&Vl[(q)      * 64 + ((2 | hi) ^ (q & 7)) * 8];
            bf16x8 v02 = *(const bf16x8*)&Vl[(q)      * 64 + ((4 | hi) ^ (q & 7)) * 8];
            bf16x8 v03 = *(const bf16x8*)&Vl[(q)      * 64 + ((6 | hi) ^ (q & 7)) * 8];
            bf16x8 v10 = *(const bf16x8*)&Vl[(q + 32) * 64 + ((0 | hi) ^ (q & 7)) * 8];
            bf16x8 v11 = *(const bf16x8*)&Vl[(q + 32) * 64 + ((2 | hi) ^ (q & 7)) * 8];
            bf16x8 v12 = *(const bf16x8*)&Vl[(q + 32) * 64 + ((4 | hi) ^ (q & 7)) * 8];
            bf16x8 v13 = *(const bf16x8*)&Vl[(q + 32) * 64 + ((6 | hi) ^ (q & 7)) * 8];
            __builtin_amdgcn_s_setprio(1);
            oacc0 = __builtin_amdgcn_mfma_f32_32x32x16_bf16(v00, pf0.v, oacc0, 0, 0, 0);
            oacc1 = __builtin_amdgcn_mfma_f32_32x32x16_bf16(v10, pf0.v, oacc1, 0, 0, 0);
            oacc0 = __builtin_amdgcn_mfma_f32_32x32x16_bf16(v01, pf1.v, oacc0, 0, 0, 0);
            oacc1 = __builtin_amdgcn_mfma_f32_32x32x16_bf16(v11, pf1.v, oacc1, 0, 0, 0);
            oacc0 = __builtin_amdgcn_mfma_f32_32x32x16_bf16(v02, pf2.v, oacc0, 0, 0, 0);
            oacc1 = __builtin_amdgcn_mfma_f32_32x32x16_bf16(v12, pf2.v, oacc1, 0, 0, 0);
            oacc0 = __builtin_amdgcn_mfma_f32_32x32x16_bf16(v03, pf3.v, oacc0, 0, 0, 0);
            oacc1 = __builtin_amdgcn_mfma_f32_32x32x16_bf16(v13, pf3.v, oacc1, 0, 0, 0);
            __builtin_amdgcn_s_setprio(0);
        }

        __syncthreads();
    }

    float l_ = la + lb;
    const float lfull = l_ + __shfl_xor(l_, 32);
    const float invl = 1.f / lfull;
    const int wbase = w * 2048;
#pragma unroll
    for (int r = 0; r < 16; r++) {
        const int dk0 = (r & 3) + 8 * (r >> 2) + 4 * hi;
        const int dk1 = 32 + dk0;
        smem[wbase + q * 64 + (((dk0 >> 3) ^ (q & 7)) << 3) + (dk0 & 7)] = bfbits(oacc0[r] * invl);
        smem[wbase + q * 64 + (((dk1 >> 3) ^ (q & 7)) << 3) + (dk1 & 7)] = bfbits(oacc1[r] * invl);
    }
    __syncthreads();
    const int b = bh >> 4, h = bh & 15;
    const int r4 = lane >> 1;
    const int cc = (lane & 1) * 4;
#pragma unroll
    for (int c = 0; c < 4; c++) {
        const int chunk = cc + c;
        uint4 val = *(const uint4*)&smem[wbase + r4 * 64 + ((chunk ^ (r4 & 7)) << 3)];
        *(uint4*)&ctx[((size_t)(b * SEQ + q0 + r4)) * DMODEL + h * DK + chunk * 8] = val;
    }
}

// ---------------- in-place LayerNorm ----------------
__global__ __launch_bounds__(256) void ln_inplace(float* __restrict__ y,
                                                  const float* __restrict__ gamma,
                                                  const float* __restrict__ beta) {
    const int row = blockIdx.x;
    float* p = y + (size_t)row * DMODEL;
    const int tid = threadIdx.x;
    float4 v = *(const float4*)(p + tid * 4);
    float s  = v.x + v.y + v.z + v.w;
    float sq = v.x * v.x + v.y * v.y + v.z * v.z + v.w * v.w;
#pragma unroll
    for (int m = 1; m < 64; m <<= 1) {
        s  += __shfl_xor(s, m);
        sq += __shfl_xor(sq, m);
    }
    __shared__ float rs[4], rq[4];
    if ((tid & 63) == 0) { rs[tid >> 6] = s; rq[tid >> 6] = sq; }
    __syncthreads();
    s  = rs[0] + rs[1] + rs[2] + rs[3];
    sq = rq[0] + rq[1] + rq[2] + rq[3];
    const float mean = s * (1.0f / 1024.0f);
    const float var  = sq * (1.0f / 1024.0f) - mean * mean;
    const float inv  = rsqrtf(var + 1e-5f);
    const int c = tid * 4;
    float4 g4 = *(const float4*)(gamma + c);
    float4 b4 = *(const float4*)(beta + c);
    float4 o;
    o.x = (v.x - mean) * inv * g4.x + b4.x;
    o.y = (v.y - mean) * inv * g4.y + b4.y;
    o.z = (v.z - mean) * inv * g4.z + b4.z;
    o.w = (v.w - mean) * inv * g4.w + b4.w;
    *(float4*)(p + c) = o;
}

extern "C" void kernel_launch(void* const* d_in, const int* in_sizes, int n_in,
                              void* d_out, int out_size, void* d_ws, size_t ws_size,
                              hipStream_t stream) {
    const float* x     = (const float*)d_in[0];
    const float* Wq    = (const float*)d_in[1];
    const float* bq    = (const float*)d_in[2];
    const float* Wk    = (const float*)d_in[3];
    const float* bk    = (const float*)d_in[4];
    const float* Wv    = (const float*)d_in[5];
    const float* bv    = (const float*)d_in[6];
    const float* Wo    = (const float*)d_in[7];
    const float* bo    = (const float*)d_in[8];
    const float* gamma = (const float*)d_in[9];
    const float* beta  = (const float*)d_in[10];
    float* out = (float*)d_out;

    u16* x_bf    = (u16*)d_ws;
    u16* Wqkv_bf = x_bf + (size_t)NROWS * DMODEL;
    u16* Wo_bf   = Wqkv_bf + (size_t)3072 * 1024;
    u16* Q_bf    = Wo_bf + (size_t)1024 * 1024;
    u16* K_bf    = Q_bf + (size_t)64 * SEQ * DK;
    u16* Vt_bf   = K_bf + (size_t)64 * SEQ * DK;
    u16* ctx_bf  = x_bf;  // alias: x_bf dead after QKV GEMM

    cvt_all<<<12288, 256, 0, stream>>>(x, Wq, Wk, Wv, Wo,
                                       x_bf, Wqkv_bf, Wqkv_bf + 1048576,
                                       Wqkv_bf + 2097152, Wo_bf);

    gemm_piped<0><<<dim3(64, 24), 512, 0, stream>>>(x_bf, Wqkv_bf,
                                                    bq, bk, bv, Q_bf, K_bf, Vt_bf,
                                                    nullptr, nullptr);
    attn<<<dim3(64, 8), 512, 0, stream>>>(Q_bf, K_bf, Vt_bf, ctx_bf);
    gemm_piped<1><<<dim3(64, 8), 512, 0, stream>>>(ctx_bf, Wo_bf,
                                                   bo, nullptr, nullptr,
                                                   nullptr, nullptr, nullptr,
                                                   x, out);
    ln_inplace<<<8192, 256, 0, stream>>>(out, gamma, beta);
}